// Round 1
// baseline (3205.145 us; speedup 1.0000x reference)
//
#include <hip/hip_runtime.h>

#define Nn 100000
#define Ee 1600000
#define Pp 1000000
#define EPSf 1e-5f

__device__ __forceinline__ float4 ld4(const float* p) { return *(const float4*)p; }

// ---------------- CSR build ----------------
__global__ __launch_bounds__(256) void hist_kernel(const int* __restrict__ dst,
                                                   unsigned* __restrict__ deg) {
    int i = blockIdx.x * 256 + threadIdx.x;
    if (i < Ee) atomicAdd(&deg[dst[i]], 1u);
}

__global__ __launch_bounds__(1024) void scan_kernel(const unsigned* __restrict__ deg,
                                                    int* __restrict__ rowptr,
                                                    int* __restrict__ cursor) {
    __shared__ unsigned ssum[1024];
    int t = threadIdx.x;
    const int CH = (Nn + 1023) / 1024;   // 98
    int beg = t * CH;
    int end = min(beg + CH, Nn);
    unsigned s = 0;
    for (int i = beg; i < end; ++i) s += deg[i];
    ssum[t] = s;
    __syncthreads();
    for (int off = 1; off < 1024; off <<= 1) {
        unsigned v = (t >= off) ? ssum[t - off] : 0u;
        __syncthreads();
        ssum[t] += v;
        __syncthreads();
    }
    unsigned run = ssum[t] - s;   // exclusive prefix
    for (int i = beg; i < end; ++i) {
        rowptr[i] = (int)run;
        cursor[i] = (int)run;
        run += deg[i];
    }
    if (t == 1023) rowptr[Nn] = (int)ssum[1023];
}

__global__ __launch_bounds__(256) void scatter_kernel(const int* __restrict__ src,
                                                      const int* __restrict__ dst,
                                                      int* __restrict__ cursor,
                                                      int* __restrict__ elist) {
    int i = blockIdx.x * 256 + threadIdx.x;
    if (i < Ee) {
        int p = atomicAdd(&cursor[dst[i]], 1);
        elist[p] = src[i];
    }
}

// ---------------- mean aggregation: one wave per node ----------------
__global__ __launch_bounds__(256) void aggregate_kernel(const float* __restrict__ feat,  // [N,128]
                                                        const int* __restrict__ rowptr,
                                                        const int* __restrict__ elist,
                                                        float* __restrict__ out) {       // [N,128]
    int node = (blockIdx.x * 256 + threadIdx.x) >> 6;
    int lane = threadIdx.x & 63;
    if (node >= Nn) return;
    int beg = rowptr[node], end = rowptr[node + 1];
    float ax = 0.f, ay = 0.f;
    for (int j = beg; j < end; ++j) {
        int s = elist[j];
        float2 v = *(const float2*)(feat + s * 128 + lane * 2);
        ax += v.x; ay += v.y;
    }
    float inv = 1.0f / fmaxf((float)(end - beg), 1.0f);
    float2 r; r.x = ax * inv; r.y = ay * inv;
    *(float2*)(out + node * 128 + lane * 2) = r;
}

// ---------------- dense SAGE: out = act( A1@W1^T + A2@W2^T + lb [, bn+relu] ) ----------
// M=100000, K=128 each source. Tile 64 rows x NOUT cols per block, 256 threads.
template<int NOUT, bool BNRELU>
__global__ __launch_bounds__(256) void dense_sage_kernel(
    const float* __restrict__ A1, const float* __restrict__ A2,
    const float* __restrict__ W1, const float* __restrict__ W2,   // [NOUT,128] each
    const float* __restrict__ lb,
    const float* __restrict__ bng, const float* __restrict__ bnb,
    const float* __restrict__ bnm, const float* __restrict__ bnv,
    float* __restrict__ out) {
    constexpr int CPT = NOUT / 16;   // cols per thread (8 or 4)
    __shared__ float sA[64][33];
    __shared__ float sW[NOUT][33];
    const int t  = threadIdx.x;
    const int m0 = blockIdx.x * 64;
    const int r0 = (t >> 4) * 4;        // lanes 0..15 share r0 -> sA broadcast
    const int c0 = (t & 15) * CPT;      // contiguous col group -> coalesced stores
    float acc[4][CPT];
#pragma unroll
    for (int i = 0; i < 4; ++i)
#pragma unroll
        for (int j = 0; j < CPT; ++j) acc[i][j] = 0.f;

    for (int half = 0; half < 2; ++half) {
        const float* __restrict__ A = half ? A2 : A1;
        const float* __restrict__ W = half ? W2 : W1;
        for (int k0 = 0; k0 < 128; k0 += 32) {
            __syncthreads();
            // A tile 64x32
#pragma unroll
            for (int p = 0; p < 2; ++p) {
                int idx = t + p * 256;
                int row = idx >> 3, cg = idx & 7;
                int gr = m0 + row;
                float4 v = make_float4(0.f, 0.f, 0.f, 0.f);
                if (gr < Nn) v = ld4(A + gr * 128 + k0 + cg * 4);
                sA[row][cg * 4 + 0] = v.x; sA[row][cg * 4 + 1] = v.y;
                sA[row][cg * 4 + 2] = v.z; sA[row][cg * 4 + 3] = v.w;
            }
            // W tile NOUTx32
#pragma unroll
            for (int p = 0; p < NOUT / 32; ++p) {
                int idx = t + p * 256;
                int row = idx >> 3, cg = idx & 7;
                float4 v = ld4(W + row * 128 + k0 + cg * 4);
                sW[row][cg * 4 + 0] = v.x; sW[row][cg * 4 + 1] = v.y;
                sW[row][cg * 4 + 2] = v.z; sW[row][cg * 4 + 3] = v.w;
            }
            __syncthreads();
#pragma unroll
            for (int k = 0; k < 32; ++k) {
                float a0 = sA[r0 + 0][k], a1 = sA[r0 + 1][k];
                float a2 = sA[r0 + 2][k], a3 = sA[r0 + 3][k];
#pragma unroll
                for (int j = 0; j < CPT; ++j) {
                    float w = sW[c0 + j][k];
                    acc[0][j] += a0 * w; acc[1][j] += a1 * w;
                    acc[2][j] += a2 * w; acc[3][j] += a3 * w;
                }
            }
        }
    }
    // epilogue
    float sc[CPT], sh[CPT];
#pragma unroll
    for (int j = 0; j < CPT; ++j) {
        int c = c0 + j;
        if constexpr (BNRELU) {
            float s = bng[c] * rsqrtf(bnv[c] + EPSf);
            sc[j] = s;
            sh[j] = (lb[c] - bnm[c]) * s + bnb[c];
        } else {
            sc[j] = 1.f; sh[j] = lb[c];
        }
    }
#pragma unroll
    for (int i = 0; i < 4; ++i) {
        int gr = m0 + r0 + i;
        if (gr < Nn) {
            float vals[CPT];
#pragma unroll
            for (int j = 0; j < CPT; ++j) {
                float v = acc[i][j] * sc[j] + sh[j];
                if constexpr (BNRELU) v = fmaxf(v, 0.f);
                vals[j] = v;
            }
#pragma unroll
            for (int j = 0; j < CPT; j += 4) {
                *(float4*)(out + gr * NOUT + c0 + j) =
                    make_float4(vals[j], vals[j + 1], vals[j + 2], vals[j + 3]);
            }
        }
    }
}

// ---------------- projection: Za = z@W1a^T, Zb = z@W1b^T  (K=64, NOUT=128) ------------
__global__ __launch_bounds__(256) void proj_kernel(const float* __restrict__ z,     // [N,64]
                                                   const float* __restrict__ pW1,   // [128,160]
                                                   float* __restrict__ Za,
                                                   float* __restrict__ Zb) {
    __shared__ float sZ[64][65];
    __shared__ float sW[128][65];
    const int t  = threadIdx.x;
    const int m0 = blockIdx.x * 64;
    const int woff = blockIdx.y ? 64 : 0;
    float* __restrict__ out = blockIdx.y ? Zb : Za;
    // load z tile 64x64
#pragma unroll
    for (int p = 0; p < 4; ++p) {
        int idx = t + p * 256;
        int row = idx >> 4, cg = idx & 15;
        int gr = m0 + row;
        float4 v = make_float4(0.f, 0.f, 0.f, 0.f);
        if (gr < Nn) v = ld4(z + gr * 64 + cg * 4);
        sZ[row][cg * 4 + 0] = v.x; sZ[row][cg * 4 + 1] = v.y;
        sZ[row][cg * 4 + 2] = v.z; sZ[row][cg * 4 + 3] = v.w;
    }
    // load W tile 128x64 (cols woff..woff+63 of pW1, row stride 160)
#pragma unroll
    for (int p = 0; p < 8; ++p) {
        int idx = t + p * 256;
        int row = idx >> 4, cg = idx & 15;
        float4 v = ld4(pW1 + row * 160 + woff + cg * 4);
        sW[row][cg * 4 + 0] = v.x; sW[row][cg * 4 + 1] = v.y;
        sW[row][cg * 4 + 2] = v.z; sW[row][cg * 4 + 3] = v.w;
    }
    __syncthreads();
    const int r0 = (t >> 4) * 4;
    const int c0 = (t & 15) * 8;
    float acc[4][8];
#pragma unroll
    for (int i = 0; i < 4; ++i)
#pragma unroll
        for (int j = 0; j < 8; ++j) acc[i][j] = 0.f;
#pragma unroll 4
    for (int k = 0; k < 64; ++k) {
        float a0 = sZ[r0 + 0][k], a1 = sZ[r0 + 1][k];
        float a2 = sZ[r0 + 2][k], a3 = sZ[r0 + 3][k];
#pragma unroll
        for (int j = 0; j < 8; ++j) {
            float w = sW[c0 + j][k];
            acc[0][j] += a0 * w; acc[1][j] += a1 * w;
            acc[2][j] += a2 * w; acc[3][j] += a3 * w;
        }
    }
#pragma unroll
    for (int i = 0; i < 4; ++i) {
        int gr = m0 + r0 + i;
        if (gr < Nn) {
            *(float4*)(out + gr * 128 + c0 + 0) = make_float4(acc[i][0], acc[i][1], acc[i][2], acc[i][3]);
            *(float4*)(out + gr * 128 + c0 + 4) = make_float4(acc[i][4], acc[i][5], acc[i][6], acc[i][7]);
        }
    }
}

// ---------------- fused per-edge predictor ----------------
// 32 edges / block, 256 threads. Edge MLP -> gather Za/Zb -> BN/ReLU -> GEMM -> BN/ReLU -> dot
#define EPB 32
__global__ __launch_bounds__(256) void edge_kernel(
    const int* __restrict__ pe,      // [2,P]
    const float* __restrict__ ef,    // [P,32]
    const float* __restrict__ Za,    // [N,128]
    const float* __restrict__ Zb,    // [N,128]
    const float* __restrict__ eW1, const float* __restrict__ eb1,
    const float* __restrict__ ebng, const float* __restrict__ ebnb,
    const float* __restrict__ ebnm, const float* __restrict__ ebnv,
    const float* __restrict__ eW2, const float* __restrict__ eb2,
    const float* __restrict__ pW1, const float* __restrict__ pb1,
    const float* __restrict__ p1g, const float* __restrict__ p1b,
    const float* __restrict__ p1m, const float* __restrict__ p1v,
    const float* __restrict__ pW2, const float* __restrict__ pb2,
    const float* __restrict__ p2g, const float* __restrict__ p2b,
    const float* __restrict__ p2m, const float* __restrict__ p2v,
    const float* __restrict__ pW3, const float* __restrict__ pb3,
    float* __restrict__ out) {
    __shared__ float sEF[EPB][33];
    __shared__ float sE1[EPB][65];
    __shared__ float sE2[EPB][33];
    __shared__ float sU1[EPB][130];
    __shared__ float sU2[EPB][65];
    __shared__ int   sAI[EPB], sBI[EPB];
    __shared__ float s_e_s[64],  s_e_h[64];
    __shared__ float s_1_s[128], s_1_h[128];
    __shared__ float s_2_s[64],  s_2_h[64];

    const int t = threadIdx.x;
    const int base = blockIdx.x * EPB;

    if (t < EPB)            sAI[t] = pe[base + t];
    else if (t < 2 * EPB)   sBI[t - EPB] = pe[Pp + base + (t - EPB)];

    if (t < 64) {
        float s = ebng[t] * rsqrtf(ebnv[t] + EPSf);
        s_e_s[t] = s; s_e_h[t] = (eb1[t] - ebnm[t]) * s + ebnb[t];
    } else if (t < 192) {
        int c = t - 64;
        float s = p1g[c] * rsqrtf(p1v[c] + EPSf);
        s_1_s[c] = s; s_1_h[c] = (pb1[c] - p1m[c]) * s + p1b[c];
    } else {
        int c = t - 192;
        float s = p2g[c] * rsqrtf(p2v[c] + EPSf);
        s_2_s[c] = s; s_2_h[c] = (pb2[c] - p2m[c]) * s + p2b[c];
    }
    { // edge-feature tile 32x32 (one float4 per thread)
        int row = t >> 3, cg = t & 7;
        float4 v = ld4(ef + (base + row) * 32 + cg * 4);
        sEF[row][cg * 4 + 0] = v.x; sEF[row][cg * 4 + 1] = v.y;
        sEF[row][cg * 4 + 2] = v.z; sEF[row][cg * 4 + 3] = v.w;
    }
    __syncthreads();

    // ---- P2: e1 = relu(bn(ef @ eW1^T + eb1))  [32x64], 8 ch/thread, K=32
    {
        int e = t & 31, cg = t >> 5;
        float a[32];
#pragma unroll
        for (int k = 0; k < 32; ++k) a[k] = sEF[e][k];
#pragma unroll
        for (int j = 0; j < 8; ++j) {
            int c = cg * 8 + j;
            const float* wr = eW1 + c * 32;
            float acc = 0.f;
#pragma unroll
            for (int k = 0; k < 32; k += 4) {
                float4 w = ld4(wr + k);
                acc += a[k] * w.x + a[k + 1] * w.y + a[k + 2] * w.z + a[k + 3] * w.w;
            }
            sE1[e][c] = fmaxf(acc * s_e_s[c] + s_e_h[c], 0.f);
        }
    }
    __syncthreads();

    // ---- P3: e2 = e1 @ eW2^T + eb2  [32x32], 4 ch/thread, K=64
    {
        int e = t & 31, cg = t >> 5;
        float a[64];
#pragma unroll
        for (int k = 0; k < 64; ++k) a[k] = sE1[e][k];
#pragma unroll
        for (int j = 0; j < 4; ++j) {
            int c = cg * 4 + j;
            const float* wr = eW2 + c * 64;
            float acc = 0.f;
#pragma unroll
            for (int k = 0; k < 64; k += 4) {
                float4 w = ld4(wr + k);
                acc += a[k] * w.x + a[k + 1] * w.y + a[k + 2] * w.z + a[k + 3] * w.w;
            }
            sE2[e][c] = acc + eb2[c];
        }
    }
    __syncthreads();

    // ---- P4a: sU1[e][c] = Za[a_e][c] + Zb[b_e][c]   (coalesced float2 rows)
    {
        int w = t >> 6, l = t & 63;
        for (int e = w; e < EPB; e += 4) {
            int ai = sAI[e], bi = sBI[e];
            float2 va = *(const float2*)(Za + ai * 128 + l * 2);
            float2 vb = *(const float2*)(Zb + bi * 128 + l * 2);
            float2 r; r.x = va.x + vb.x; r.y = va.y + vb.y;
            *(float2*)(&sU1[e][l * 2]) = r;
        }
    }
    __syncthreads();

    // ---- P4b: u1 = relu(bn1(gather + e2 @ W1c^T + pb1))  [32x128], 16 ch/thread, K=32
    {
        int e = t & 31, cg = t >> 5;
        float a[32];
#pragma unroll
        for (int k = 0; k < 32; ++k) a[k] = sE2[e][k];
#pragma unroll
        for (int j = 0; j < 16; ++j) {
            int c = cg * 16 + j;
            const float* wr = pW1 + c * 160 + 128;
            float acc = 0.f;
#pragma unroll
            for (int k = 0; k < 32; k += 4) {
                float4 w = ld4(wr + k);
                acc += a[k] * w.x + a[k + 1] * w.y + a[k + 2] * w.z + a[k + 3] * w.w;
            }
            float u = sU1[e][c] + acc;
            sU1[e][c] = fmaxf(u * s_1_s[c] + s_1_h[c], 0.f);
        }
    }
    __syncthreads();

    // ---- P6: u2 = relu(bn2(u1 @ pW2^T + pb2))  [32x64], 8 ch/thread, K=128
    {
        int e = t & 31, cg = t >> 5;
        float acc[8];
#pragma unroll
        for (int j = 0; j < 8; ++j) acc[j] = 0.f;
        for (int k0 = 0; k0 < 128; k0 += 32) {
            float a[32];
#pragma unroll
            for (int k = 0; k < 32; ++k) a[k] = sU1[e][k0 + k];
#pragma unroll
            for (int j = 0; j < 8; ++j) {
                int c = cg * 8 + j;
                const float* wr = pW2 + c * 128 + k0;
#pragma unroll
                for (int k = 0; k < 32; k += 4) {
                    float4 w = ld4(wr + k);
                    acc[j] += a[k] * w.x + a[k + 1] * w.y + a[k + 2] * w.z + a[k + 3] * w.w;
                }
            }
        }
#pragma unroll
        for (int j = 0; j < 8; ++j) {
            int c = cg * 8 + j;
            sU2[e][c] = fmaxf(acc[j] * s_2_s[c] + s_2_h[c], 0.f);
        }
    }
    __syncthreads();

    // ---- P7: out = u2 @ pW3^T + pb3
    if (t < EPB) {
        float acc = 0.f;
#pragma unroll
        for (int k = 0; k < 64; ++k) acc += sU2[t][k] * pW3[k];
        out[base + t] = acc + pb3[0];
    }
}

// ---------------- launch ----------------
extern "C" void kernel_launch(void* const* d_in, const int* in_sizes, int n_in,
                              void* d_out, int out_size, void* d_ws, size_t ws_size,
                              hipStream_t stream) {
    const float* x    = (const float*)d_in[0];
    const int*   eidx = (const int*)d_in[1];
    const int*   pe   = (const int*)d_in[2];
    const float* ef   = (const float*)d_in[3];
    const float* s1Wl = (const float*)d_in[4];
    const float* s1bl = (const float*)d_in[5];
    const float* s1Wr = (const float*)d_in[6];
    const float* bn1g = (const float*)d_in[7];
    const float* bn1b = (const float*)d_in[8];
    const float* bn1m = (const float*)d_in[9];
    const float* bn1v = (const float*)d_in[10];
    const float* s2Wl = (const float*)d_in[11];
    const float* s2bl = (const float*)d_in[12];
    const float* s2Wr = (const float*)d_in[13];
    const float* eW1  = (const float*)d_in[14];
    const float* eb1  = (const float*)d_in[15];
    const float* ebng = (const float*)d_in[16];
    const float* ebnb = (const float*)d_in[17];
    const float* ebnm = (const float*)d_in[18];
    const float* ebnv = (const float*)d_in[19];
    const float* eW2  = (const float*)d_in[20];
    const float* eb2  = (const float*)d_in[21];
    const float* pW1  = (const float*)d_in[22];
    const float* pb1  = (const float*)d_in[23];
    const float* p1g  = (const float*)d_in[24];
    const float* p1b  = (const float*)d_in[25];
    const float* p1m  = (const float*)d_in[26];
    const float* p1v  = (const float*)d_in[27];
    const float* pW2  = (const float*)d_in[28];
    const float* pb2  = (const float*)d_in[29];
    const float* p2g  = (const float*)d_in[30];
    const float* p2b  = (const float*)d_in[31];
    const float* p2m  = (const float*)d_in[32];
    const float* p2v  = (const float*)d_in[33];
    const float* pW3  = (const float*)d_in[34];
    const float* pb3  = (const float*)d_in[35];
    float* out = (float*)d_out;

    // workspace carve (≈136 MB)
    char* w = (char*)d_ws;
    auto carve = [&](size_t bytes) {
        char* p = w;
        w += (bytes + 255) & ~(size_t)255;
        return p;
    };
    unsigned* deg    = (unsigned*)carve((size_t)Nn * 4);
    int*      rowptr = (int*)carve((size_t)(Nn + 1) * 4);
    int*      cursor = (int*)carve((size_t)Nn * 4);
    int*      elist  = (int*)carve((size_t)Ee * 4);
    float*    bufA   = (float*)carve((size_t)Nn * 128 * 4);  // agg1 / agg2 / Za
    float*    bufB   = (float*)carve((size_t)Nn * 128 * 4);  // h1 / Zb
    float*    bufC   = (float*)carve((size_t)Nn * 64 * 4);   // z

    const int* e_src = eidx;        // edge_index[0]
    const int* e_dst = eidx + Ee;   // edge_index[1]

    hipMemsetAsync(deg, 0, (size_t)Nn * 4, stream);
    hist_kernel<<<(Ee + 255) / 256, 256, 0, stream>>>(e_dst, deg);
    scan_kernel<<<1, 1024, 0, stream>>>(deg, rowptr, cursor);
    scatter_kernel<<<(Ee + 255) / 256, 256, 0, stream>>>(e_src, e_dst, cursor, elist);

    // SAGE layer 1
    aggregate_kernel<<<Nn / 4, 256, 0, stream>>>(x, rowptr, elist, bufA);
    dense_sage_kernel<128, true><<<(Nn + 63) / 64, 256, 0, stream>>>(
        bufA, x, s1Wl, s1Wr, s1bl, bn1g, bn1b, bn1m, bn1v, bufB);

    // SAGE layer 2
    aggregate_kernel<<<Nn / 4, 256, 0, stream>>>(bufB, rowptr, elist, bufA);
    dense_sage_kernel<64, false><<<(Nn + 63) / 64, 256, 0, stream>>>(
        bufA, bufB, s2Wl, s2Wr, s2bl, nullptr, nullptr, nullptr, nullptr, bufC);

    // node-side projection of predictor W1 (Za into bufA, Zb into bufB)
    proj_kernel<<<dim3((Nn + 63) / 64, 2), 256, 0, stream>>>(bufC, pW1, bufA, bufB);

    // fused per-edge predictor
    edge_kernel<<<Pp / EPB, 256, 0, stream>>>(
        pe, ef, bufA, bufB,
        eW1, eb1, ebng, ebnb, ebnm, ebnv, eW2, eb2,
        pW1, pb1, p1g, p1b, p1m, p1v,
        pW2, pb2, p2g, p2b, p2m, p2v,
        pW3, pb3, out);
}

// Round 2
// 1668.433 us; speedup vs baseline: 1.9211x; 1.9211x over previous
//
#include <hip/hip_runtime.h>

#define Nn 100000
#define Ee 1600000
#define Pp 1000000
#define EPSf 1e-5f

typedef _Float16 f16x8 __attribute__((ext_vector_type(8)));
typedef _Float16 f16x4 __attribute__((ext_vector_type(4)));
typedef _Float16 f16x2 __attribute__((ext_vector_type(2)));
typedef float f32x4 __attribute__((ext_vector_type(4)));

__device__ __forceinline__ float4 ld4(const float* p) { return *(const float4*)p; }

// ---------------- CSR build ----------------
__global__ __launch_bounds__(256) void hist_kernel(const int* __restrict__ dst,
                                                   unsigned* __restrict__ deg) {
    int i = blockIdx.x * 256 + threadIdx.x;
    if (i < Ee) atomicAdd(&deg[dst[i]], 1u);
}

__global__ __launch_bounds__(1024) void scan_kernel(const unsigned* __restrict__ deg,
                                                    int* __restrict__ rowptr,
                                                    int* __restrict__ cursor) {
    __shared__ unsigned ssum[1024];
    int t = threadIdx.x;
    const int CH = (Nn + 1023) / 1024;
    int beg = t * CH;
    int end = min(beg + CH, Nn);
    unsigned s = 0;
    for (int i = beg; i < end; ++i) s += deg[i];
    ssum[t] = s;
    __syncthreads();
    for (int off = 1; off < 1024; off <<= 1) {
        unsigned v = (t >= off) ? ssum[t - off] : 0u;
        __syncthreads();
        ssum[t] += v;
        __syncthreads();
    }
    unsigned run = ssum[t] - s;
    for (int i = beg; i < end; ++i) {
        rowptr[i] = (int)run;
        cursor[i] = (int)run;
        run += deg[i];
    }
    if (t == 1023) rowptr[Nn] = (int)ssum[1023];
}

__global__ __launch_bounds__(256) void scatter_kernel(const int* __restrict__ src,
                                                      const int* __restrict__ dst,
                                                      int* __restrict__ cursor,
                                                      int* __restrict__ elist) {
    int i = blockIdx.x * 256 + threadIdx.x;
    if (i < Ee) {
        int p = atomicAdd(&cursor[dst[i]], 1);
        elist[p] = src[i];
    }
}

// ---------------- mean aggregation: one wave per node ----------------
__global__ __launch_bounds__(256) void aggregate_kernel(const float* __restrict__ feat,
                                                        const int* __restrict__ rowptr,
                                                        const int* __restrict__ elist,
                                                        float* __restrict__ out) {
    int node = (blockIdx.x * 256 + threadIdx.x) >> 6;
    int lane = threadIdx.x & 63;
    if (node >= Nn) return;
    int beg = rowptr[node], end = rowptr[node + 1];
    float ax = 0.f, ay = 0.f;
    for (int j = beg; j < end; ++j) {
        int s = elist[j];
        float2 v = *(const float2*)(feat + s * 128 + lane * 2);
        ax += v.x; ay += v.y;
    }
    float inv = 1.0f / fmaxf((float)(end - beg), 1.0f);
    float2 r; r.x = ax * inv; r.y = ay * inv;
    *(float2*)(out + node * 128 + lane * 2) = r;
}

// ---------------- dense SAGE (fp32 register-tiled, unchanged) ----------------
template<int NOUT, bool BNRELU>
__global__ __launch_bounds__(256) void dense_sage_kernel(
    const float* __restrict__ A1, const float* __restrict__ A2,
    const float* __restrict__ W1, const float* __restrict__ W2,
    const float* __restrict__ lb,
    const float* __restrict__ bng, const float* __restrict__ bnb,
    const float* __restrict__ bnm, const float* __restrict__ bnv,
    float* __restrict__ out) {
    constexpr int CPT = NOUT / 16;
    __shared__ float sA[64][33];
    __shared__ float sW[NOUT][33];
    const int t  = threadIdx.x;
    const int m0 = blockIdx.x * 64;
    const int r0 = (t >> 4) * 4;
    const int c0 = (t & 15) * CPT;
    float acc[4][CPT];
#pragma unroll
    for (int i = 0; i < 4; ++i)
#pragma unroll
        for (int j = 0; j < CPT; ++j) acc[i][j] = 0.f;

    for (int half = 0; half < 2; ++half) {
        const float* __restrict__ A = half ? A2 : A1;
        const float* __restrict__ W = half ? W2 : W1;
        for (int k0 = 0; k0 < 128; k0 += 32) {
            __syncthreads();
#pragma unroll
            for (int p = 0; p < 2; ++p) {
                int idx = t + p * 256;
                int row = idx >> 3, cg = idx & 7;
                int gr = m0 + row;
                float4 v = make_float4(0.f, 0.f, 0.f, 0.f);
                if (gr < Nn) v = ld4(A + gr * 128 + k0 + cg * 4);
                sA[row][cg * 4 + 0] = v.x; sA[row][cg * 4 + 1] = v.y;
                sA[row][cg * 4 + 2] = v.z; sA[row][cg * 4 + 3] = v.w;
            }
#pragma unroll
            for (int p = 0; p < NOUT / 32; ++p) {
                int idx = t + p * 256;
                int row = idx >> 3, cg = idx & 7;
                float4 v = ld4(W + row * 128 + k0 + cg * 4);
                sW[row][cg * 4 + 0] = v.x; sW[row][cg * 4 + 1] = v.y;
                sW[row][cg * 4 + 2] = v.z; sW[row][cg * 4 + 3] = v.w;
            }
            __syncthreads();
#pragma unroll
            for (int k = 0; k < 32; ++k) {
                float a0 = sA[r0 + 0][k], a1 = sA[r0 + 1][k];
                float a2 = sA[r0 + 2][k], a3 = sA[r0 + 3][k];
#pragma unroll
                for (int j = 0; j < CPT; ++j) {
                    float w = sW[c0 + j][k];
                    acc[0][j] += a0 * w; acc[1][j] += a1 * w;
                    acc[2][j] += a2 * w; acc[3][j] += a3 * w;
                }
            }
        }
    }
    float sc[CPT], sh[CPT];
#pragma unroll
    for (int j = 0; j < CPT; ++j) {
        int c = c0 + j;
        if constexpr (BNRELU) {
            float s = bng[c] * rsqrtf(bnv[c] + EPSf);
            sc[j] = s;
            sh[j] = (lb[c] - bnm[c]) * s + bnb[c];
        } else {
            sc[j] = 1.f; sh[j] = lb[c];
        }
    }
#pragma unroll
    for (int i = 0; i < 4; ++i) {
        int gr = m0 + r0 + i;
        if (gr < Nn) {
            float vals[CPT];
#pragma unroll
            for (int j = 0; j < CPT; ++j) {
                float v = acc[i][j] * sc[j] + sh[j];
                if constexpr (BNRELU) v = fmaxf(v, 0.f);
                vals[j] = v;
            }
#pragma unroll
            for (int j = 0; j < CPT; j += 4) {
                *(float4*)(out + gr * NOUT + c0 + j) =
                    make_float4(vals[j], vals[j + 1], vals[j + 2], vals[j + 3]);
            }
        }
    }
}

// ---------------- projection: Za = z@W1a^T, Zb = z@W1b^T ----------------
__global__ __launch_bounds__(256) void proj_kernel(const float* __restrict__ z,
                                                   const float* __restrict__ pW1,
                                                   float* __restrict__ Za,
                                                   float* __restrict__ Zb) {
    __shared__ float sZ[64][65];
    __shared__ float sW[128][65];
    const int t  = threadIdx.x;
    const int m0 = blockIdx.x * 64;
    const int woff = blockIdx.y ? 64 : 0;
    float* __restrict__ out = blockIdx.y ? Zb : Za;
#pragma unroll
    for (int p = 0; p < 4; ++p) {
        int idx = t + p * 256;
        int row = idx >> 4, cg = idx & 15;
        int gr = m0 + row;
        float4 v = make_float4(0.f, 0.f, 0.f, 0.f);
        if (gr < Nn) v = ld4(z + gr * 64 + cg * 4);
        sZ[row][cg * 4 + 0] = v.x; sZ[row][cg * 4 + 1] = v.y;
        sZ[row][cg * 4 + 2] = v.z; sZ[row][cg * 4 + 3] = v.w;
    }
#pragma unroll
    for (int p = 0; p < 8; ++p) {
        int idx = t + p * 256;
        int row = idx >> 4, cg = idx & 15;
        float4 v = ld4(pW1 + row * 160 + woff + cg * 4);
        sW[row][cg * 4 + 0] = v.x; sW[row][cg * 4 + 1] = v.y;
        sW[row][cg * 4 + 2] = v.z; sW[row][cg * 4 + 3] = v.w;
    }
    __syncthreads();
    const int r0 = (t >> 4) * 4;
    const int c0 = (t & 15) * 8;
    float acc[4][8];
#pragma unroll
    for (int i = 0; i < 4; ++i)
#pragma unroll
        for (int j = 0; j < 8; ++j) acc[i][j] = 0.f;
#pragma unroll 4
    for (int k = 0; k < 64; ++k) {
        float a0 = sZ[r0 + 0][k], a1 = sZ[r0 + 1][k];
        float a2 = sZ[r0 + 2][k], a3 = sZ[r0 + 3][k];
#pragma unroll
        for (int j = 0; j < 8; ++j) {
            float w = sW[c0 + j][k];
            acc[0][j] += a0 * w; acc[1][j] += a1 * w;
            acc[2][j] += a2 * w; acc[3][j] += a3 * w;
        }
    }
#pragma unroll
    for (int i = 0; i < 4; ++i) {
        int gr = m0 + r0 + i;
        if (gr < Nn) {
            *(float4*)(out + gr * 128 + c0 + 0) = make_float4(acc[i][0], acc[i][1], acc[i][2], acc[i][3]);
            *(float4*)(out + gr * 128 + c0 + 4) = make_float4(acc[i][4], acc[i][5], acc[i][6], acc[i][7]);
        }
    }
}

// ---------------- fused per-edge predictor: f16 MFMA ----------------
// 64 edges/block, 4 waves; wave w owns edges [w*16, w*16+16) end-to-end.
// All f16 LDS row strides are K+8 (mult of 8, (K+8)/8 odd) => every 8-f16
// fragment read is a 16B-aligned ds_read_b128 with bandwidth-optimal banking.
#define EPB 64

// LDS byte offsets (single 16B-aligned arena; sU2 aliases sE1)
#define oWe1 0        // eW1 f16 [64][40]   5120 B
#define oWe2 5120     // eW2 f16 [32][72]   4608 B
#define oWp1 9728     // pW1c f16 [128][40] 10240 B
#define oWp2 19968    // pW2 f16 [64][136]  17408 B
#define oWp3 37376    // pW3 f32 [64]       256 B
#define oBN  37632    // BN consts f32 [544] 2176 B
#define oEF  39808    // ef f16 [64][40]    5120 B
#define oE1  44928    // e1 f16 [64][72]    9216 B  (aliased by sU2)
#define oE2  54144    // e2 f16 [64][40]    5120 B
#define oU1  59264    // u1 f16 [64][136]   17408 B
#define SMEM_BYTES 76672

__global__ __launch_bounds__(256) void edge_kernel(
    const int* __restrict__ pe,
    const float* __restrict__ ef,
    const float* __restrict__ Za,
    const float* __restrict__ Zb,
    const float* __restrict__ eW1, const float* __restrict__ eb1,
    const float* __restrict__ ebng, const float* __restrict__ ebnb,
    const float* __restrict__ ebnm, const float* __restrict__ ebnv,
    const float* __restrict__ eW2, const float* __restrict__ eb2,
    const float* __restrict__ pW1, const float* __restrict__ pb1,
    const float* __restrict__ p1g, const float* __restrict__ p1b,
    const float* __restrict__ p1m, const float* __restrict__ p1v,
    const float* __restrict__ pW2, const float* __restrict__ pb2,
    const float* __restrict__ p2g, const float* __restrict__ p2b,
    const float* __restrict__ p2m, const float* __restrict__ p2v,
    const float* __restrict__ pW3, const float* __restrict__ pb3,
    float* __restrict__ out) {
    __shared__ __align__(16) unsigned char smem[SMEM_BYTES];
    _Float16* We1 = (_Float16*)(smem + oWe1);
    _Float16* We2 = (_Float16*)(smem + oWe2);
    _Float16* Wp1 = (_Float16*)(smem + oWp1);
    _Float16* Wp2 = (_Float16*)(smem + oWp2);
    float*    Wp3 = (float*)(smem + oWp3);
    float*    BN  = (float*)(smem + oBN);
    float* bn1s = BN;        float* bn1h = BN + 64;
    float* bn2s = BN + 128;  float* bn2h = BN + 256;
    float* bn3s = BN + 384;  float* bn3h = BN + 448;
    float* sEb2 = BN + 512;  // 32 floats
    _Float16* EF = (_Float16*)(smem + oEF);
    _Float16* E1 = (_Float16*)(smem + oE1);
    _Float16* E2 = (_Float16*)(smem + oE2);
    _Float16* U1 = (_Float16*)(smem + oU1);
    _Float16* U2 = (_Float16*)(smem + oE1);  // alias (E1 dead after P3)

    const int t = threadIdx.x;
    const int base = blockIdx.x * EPB;
    const int lane = t & 63;
    const int w = t >> 6;
    const int m0 = w * 16;
    const int lrow = lane & 15;
    const int lq = lane >> 4;

    // ---- cooperative staging: weights (f32 -> f16), BN consts ----
#pragma unroll 2
    for (int i = t; i < 512; i += 256) {           // eW1 64x32
        int r = i >> 3, c4 = i & 7;
        float4 v = ld4(eW1 + r * 32 + c4 * 4);
        f16x4 h = {(_Float16)v.x, (_Float16)v.y, (_Float16)v.z, (_Float16)v.w};
        *(f16x4*)(We1 + r * 40 + c4 * 4) = h;
    }
#pragma unroll 2
    for (int i = t; i < 512; i += 256) {           // eW2 32x64
        int r = i >> 4, c4 = i & 15;
        float4 v = ld4(eW2 + r * 64 + c4 * 4);
        f16x4 h = {(_Float16)v.x, (_Float16)v.y, (_Float16)v.z, (_Float16)v.w};
        *(f16x4*)(We2 + r * 72 + c4 * 4) = h;
    }
#pragma unroll 4
    for (int i = t; i < 1024; i += 256) {          // pW1 cols 128..159: 128x32
        int r = i >> 3, c4 = i & 7;
        float4 v = ld4(pW1 + r * 160 + 128 + c4 * 4);
        f16x4 h = {(_Float16)v.x, (_Float16)v.y, (_Float16)v.z, (_Float16)v.w};
        *(f16x4*)(Wp1 + r * 40 + c4 * 4) = h;
    }
#pragma unroll 8
    for (int i = t; i < 2048; i += 256) {          // pW2 64x128
        int r = i >> 5, c4 = i & 31;
        float4 v = ld4(pW2 + r * 128 + c4 * 4);
        f16x4 h = {(_Float16)v.x, (_Float16)v.y, (_Float16)v.z, (_Float16)v.w};
        *(f16x4*)(Wp2 + r * 136 + c4 * 4) = h;
    }
    if (t < 64) {
        Wp3[t] = pW3[t];
        float s = ebng[t] * rsqrtf(ebnv[t] + EPSf);
        bn1s[t] = s; bn1h[t] = (eb1[t] - ebnm[t]) * s + ebnb[t];
    } else if (t < 192) {
        int c = t - 64;
        float s = p1g[c] * rsqrtf(p1v[c] + EPSf);
        bn2s[c] = s; bn2h[c] = (pb1[c] - p1m[c]) * s + p1b[c];
    } else {
        int c = t - 192;
        float s = p2g[c] * rsqrtf(p2v[c] + EPSf);
        bn3s[c] = s; bn3h[c] = (pb2[c] - p2m[c]) * s + p2b[c];
    }
    if (t < 32) sEb2[t] = eb2[t];

    // ---- per-wave staging: ef rows + Za/Zb gather (wave-private rows) ----
    {   // ef: 16 rows x 32 f32; lane covers (row=lane>>2, part=lane&3)*8 cols
        int row = m0 + (lane >> 2);
        int part = lane & 3;
        const float* src = ef + (size_t)(base + row) * 32 + part * 8;
        float4 v0 = ld4(src), v1 = ld4(src + 4);
        f16x8 h = {(_Float16)v0.x, (_Float16)v0.y, (_Float16)v0.z, (_Float16)v0.w,
                   (_Float16)v1.x, (_Float16)v1.y, (_Float16)v1.z, (_Float16)v1.w};
        *(f16x8*)(EF + row * 40 + part * 8) = h;
    }
#pragma unroll 4
    for (int i = 0; i < 16; ++i) {                 // gather into U1 rows (f16)
        int e = m0 + i;
        int ai = pe[base + e];
        int bi = pe[Pp + base + e];
        float2 va = *(const float2*)(Za + (size_t)ai * 128 + 2 * lane);
        float2 vb = *(const float2*)(Zb + (size_t)bi * 128 + 2 * lane);
        f16x2 h = {(_Float16)(va.x + vb.x), (_Float16)(va.y + vb.y)};
        *(f16x2*)(U1 + e * 136 + 2 * lane) = h;
    }
    __syncthreads();

    // ---- P2: e1 = relu(bn(ef @ eW1^T)), [16x32]@[32x64] ----
    {
        f16x8 a = *(const f16x8*)(EF + (m0 + lrow) * 40 + lq * 8);
#pragma unroll
        for (int nt = 0; nt < 4; ++nt) {
            f16x8 b = *(const f16x8*)(We1 + (nt * 16 + lrow) * 40 + lq * 8);
            f32x4 c = {0.f, 0.f, 0.f, 0.f};
            c = __builtin_amdgcn_mfma_f32_16x16x32_f16(a, b, c, 0, 0, 0);
            int cc = nt * 16 + lrow;
            float s = bn1s[cc], h = bn1h[cc];
#pragma unroll
            for (int r = 0; r < 4; ++r) {
                int rr = m0 + lq * 4 + r;
                E1[rr * 72 + cc] = (_Float16)fmaxf(c[r] * s + h, 0.f);
            }
        }
    }
    // ---- P3: e2 = e1 @ eW2^T + eb2, [16x64]@[64x32] ----
    {
        f16x8 a0 = *(const f16x8*)(E1 + (m0 + lrow) * 72 + lq * 8);
        f16x8 a1 = *(const f16x8*)(E1 + (m0 + lrow) * 72 + 32 + lq * 8);
#pragma unroll
        for (int nt = 0; nt < 2; ++nt) {
            f16x8 b0 = *(const f16x8*)(We2 + (nt * 16 + lrow) * 72 + lq * 8);
            f16x8 b1 = *(const f16x8*)(We2 + (nt * 16 + lrow) * 72 + 32 + lq * 8);
            f32x4 c = {0.f, 0.f, 0.f, 0.f};
            c = __builtin_amdgcn_mfma_f32_16x16x32_f16(a0, b0, c, 0, 0, 0);
            c = __builtin_amdgcn_mfma_f32_16x16x32_f16(a1, b1, c, 0, 0, 0);
            int cc = nt * 16 + lrow;
            float bias = sEb2[cc];
#pragma unroll
            for (int r = 0; r < 4; ++r) {
                int rr = m0 + lq * 4 + r;
                E2[rr * 40 + cc] = (_Float16)(c[r] + bias);
            }
        }
    }
    // ---- P4b: u1 = relu(bn1(gather + e2 @ W1c^T)), [16x32]@[32x128] ----
    {
        f16x8 a = *(const f16x8*)(E2 + (m0 + lrow) * 40 + lq * 8);
#pragma unroll
        for (int nt = 0; nt < 8; ++nt) {
            f16x8 b = *(const f16x8*)(Wp1 + (nt * 16 + lrow) * 40 + lq * 8);
            f32x4 c = {0.f, 0.f, 0.f, 0.f};
            c = __builtin_amdgcn_mfma_f32_16x16x32_f16(a, b, c, 0, 0, 0);
            int cc = nt * 16 + lrow;
            float s = bn2s[cc], h = bn2h[cc];
#pragma unroll
            for (int r = 0; r < 4; ++r) {
                int rr = m0 + lq * 4 + r;
                float g = (float)U1[rr * 136 + cc];
                U1[rr * 136 + cc] = (_Float16)fmaxf((c[r] + g) * s + h, 0.f);
            }
        }
    }
    // ---- P6: u2 = relu(bn2(u1 @ pW2^T)), [16x128]@[128x64] ----
    {
        f16x8 a0 = *(const f16x8*)(U1 + (m0 + lrow) * 136 + 0  + lq * 8);
        f16x8 a1 = *(const f16x8*)(U1 + (m0 + lrow) * 136 + 32 + lq * 8);
        f16x8 a2 = *(const f16x8*)(U1 + (m0 + lrow) * 136 + 64 + lq * 8);
        f16x8 a3 = *(const f16x8*)(U1 + (m0 + lrow) * 136 + 96 + lq * 8);
#pragma unroll
        for (int nt = 0; nt < 4; ++nt) {
            const _Float16* wr = Wp2 + (nt * 16 + lrow) * 136 + lq * 8;
            f32x4 c = {0.f, 0.f, 0.f, 0.f};
            c = __builtin_amdgcn_mfma_f32_16x16x32_f16(a0, *(const f16x8*)(wr + 0),  c, 0, 0, 0);
            c = __builtin_amdgcn_mfma_f32_16x16x32_f16(a1, *(const f16x8*)(wr + 32), c, 0, 0, 0);
            c = __builtin_amdgcn_mfma_f32_16x16x32_f16(a2, *(const f16x8*)(wr + 64), c, 0, 0, 0);
            c = __builtin_amdgcn_mfma_f32_16x16x32_f16(a3, *(const f16x8*)(wr + 96), c, 0, 0, 0);
            int cc = nt * 16 + lrow;
            float s = bn3s[cc], h = bn3h[cc];
#pragma unroll
            for (int r = 0; r < 4; ++r) {
                int rr = m0 + lq * 4 + r;
                U2[rr * 72 + cc] = (_Float16)fmaxf(c[r] * s + h, 0.f);
            }
        }
    }
    // ---- P7: out = u2 @ pW3 + pb3 (4 lanes per edge) ----
    {
        int e = m0 + (lane >> 2);
        int c0 = (lane & 3) * 16;
        f16x8 u0 = *(const f16x8*)(U2 + e * 72 + c0);
        f16x8 u1 = *(const f16x8*)(U2 + e * 72 + c0 + 8);
        float acc = 0.f;
#pragma unroll
        for (int j = 0; j < 8; ++j) acc += (float)u0[j] * Wp3[c0 + j];
#pragma unroll
        for (int j = 0; j < 8; ++j) acc += (float)u1[j] * Wp3[c0 + 8 + j];
        acc += __shfl_xor(acc, 1);
        acc += __shfl_xor(acc, 2);
        if ((lane & 3) == 0) out[base + e] = acc + pb3[0];
    }
}

// ---------------- launch ----------------
extern "C" void kernel_launch(void* const* d_in, const int* in_sizes, int n_in,
                              void* d_out, int out_size, void* d_ws, size_t ws_size,
                              hipStream_t stream) {
    const float* x    = (const float*)d_in[0];
    const int*   eidx = (const int*)d_in[1];
    const int*   pe   = (const int*)d_in[2];
    const float* ef   = (const float*)d_in[3];
    const float* s1Wl = (const float*)d_in[4];
    const float* s1bl = (const float*)d_in[5];
    const float* s1Wr = (const float*)d_in[6];
    const float* bn1g = (const float*)d_in[7];
    const float* bn1b = (const float*)d_in[8];
    const float* bn1m = (const float*)d_in[9];
    const float* bn1v = (const float*)d_in[10];
    const float* s2Wl = (const float*)d_in[11];
    const float* s2bl = (const float*)d_in[12];
    const float* s2Wr = (const float*)d_in[13];
    const float* eW1  = (const float*)d_in[14];
    const float* eb1  = (const float*)d_in[15];
    const float* ebng = (const float*)d_in[16];
    const float* ebnb = (const float*)d_in[17];
    const float* ebnm = (const float*)d_in[18];
    const float* ebnv = (const float*)d_in[19];
    const float* eW2  = (const float*)d_in[20];
    const float* eb2  = (const float*)d_in[21];
    const float* pW1  = (const float*)d_in[22];
    const float* pb1  = (const float*)d_in[23];
    const float* p1g  = (const float*)d_in[24];
    const float* p1b  = (const float*)d_in[25];
    const float* p1m  = (const float*)d_in[26];
    const float* p1v  = (const float*)d_in[27];
    const float* pW2  = (const float*)d_in[28];
    const float* pb2  = (const float*)d_in[29];
    const float* p2g  = (const float*)d_in[30];
    const float* p2b  = (const float*)d_in[31];
    const float* p2m  = (const float*)d_in[32];
    const float* p2v  = (const float*)d_in[33];
    const float* pW3  = (const float*)d_in[34];
    const float* pb3  = (const float*)d_in[35];
    float* out = (float*)d_out;

    char* w = (char*)d_ws;
    auto carve = [&](size_t bytes) {
        char* p = w;
        w += (bytes + 255) & ~(size_t)255;
        return p;
    };
    unsigned* deg    = (unsigned*)carve((size_t)Nn * 4);
    int*      rowptr = (int*)carve((size_t)(Nn + 1) * 4);
    int*      cursor = (int*)carve((size_t)Nn * 4);
    int*      elist  = (int*)carve((size_t)Ee * 4);
    float*    bufA   = (float*)carve((size_t)Nn * 128 * 4);
    float*    bufB   = (float*)carve((size_t)Nn * 128 * 4);
    float*    bufC   = (float*)carve((size_t)Nn * 64 * 4);

    const int* e_src = eidx;
    const int* e_dst = eidx + Ee;

    hipMemsetAsync(deg, 0, (size_t)Nn * 4, stream);
    hist_kernel<<<(Ee + 255) / 256, 256, 0, stream>>>(e_dst, deg);
    scan_kernel<<<1, 1024, 0, stream>>>(deg, rowptr, cursor);
    scatter_kernel<<<(Ee + 255) / 256, 256, 0, stream>>>(e_src, e_dst, cursor, elist);

    aggregate_kernel<<<Nn / 4, 256, 0, stream>>>(x, rowptr, elist, bufA);
    dense_sage_kernel<128, true><<<(Nn + 63) / 64, 256, 0, stream>>>(
        bufA, x, s1Wl, s1Wr, s1bl, bn1g, bn1b, bn1m, bn1v, bufB);

    aggregate_kernel<<<Nn / 4, 256, 0, stream>>>(bufB, rowptr, elist, bufA);
    dense_sage_kernel<64, false><<<(Nn + 63) / 64, 256, 0, stream>>>(
        bufA, bufB, s2Wl, s2Wr, s2bl, nullptr, nullptr, nullptr, nullptr, bufC);

    proj_kernel<<<dim3((Nn + 63) / 64, 2), 256, 0, stream>>>(bufC, pW1, bufA, bufB);

    edge_kernel<<<Pp / EPB, 256, 0, stream>>>(
        pe, ef, bufA, bufB,
        eW1, eb1, ebng, ebnb, ebnm, ebnv, eW2, eb2,
        pW1, pb1, p1g, p1b, p1m, p1v,
        pW2, pb2, p2g, p2b, p2m, p2v,
        pW3, pb3, out);
}

// Round 3
// 1147.470 us; speedup vs baseline: 2.7932x; 1.4540x over previous
//
#include <hip/hip_runtime.h>

#define Nn 100000
#define Ee 1600000
#define Pp 1000000
#define EPSf 1e-5f

typedef _Float16 f16x8 __attribute__((ext_vector_type(8)));
typedef _Float16 f16x4 __attribute__((ext_vector_type(4)));
typedef _Float16 f16x2 __attribute__((ext_vector_type(2)));
typedef float f32x4 __attribute__((ext_vector_type(4)));

__device__ __forceinline__ float4 ld4(const float* p) { return *(const float4*)p; }

// f16 weight arena offsets (elements)
#define oW1l 0        // 128x128
#define oW1r 16384    // 128x128
#define oW2l 32768    // 64x128
#define oW2r 40960    // 64x128
#define oW1a 49152    // 128x64   (pW1 cols 0..63)
#define oW1b 57344    // 128x64   (pW1 cols 64..127)
#define oW1c 65536    // 128x32   (pW1 cols 128..159)
#define oWe1 69632    // 64x32
#define oWe2 71680    // 32x64
#define oWp2 73728    // 64x128
#define W16_TOTAL 81920

// ---------------- prep: f32 -> f16 for x and all GEMM weights ----------------
__global__ __launch_bounds__(256) void prep_kernel(
    const float* __restrict__ x,
    const float* __restrict__ s1Wl, const float* __restrict__ s1Wr,
    const float* __restrict__ s2Wl, const float* __restrict__ s2Wr,
    const float* __restrict__ pW1,  const float* __restrict__ eW1,
    const float* __restrict__ eW2,  const float* __restrict__ pW2,
    _Float16* __restrict__ w16, _Float16* __restrict__ x16) {
    int tid = blockIdx.x * 256 + threadIdx.x;
    if (tid < W16_TOTAL) {
        float v;
        if (tid < 16384)      v = s1Wl[tid];
        else if (tid < 32768) v = s1Wr[tid - 16384];
        else if (tid < 40960) v = s2Wl[tid - 32768];
        else if (tid < 49152) v = s2Wr[tid - 40960];
        else if (tid < 57344) { int l = tid - 49152; v = pW1[(l >> 6) * 160 + (l & 63)]; }
        else if (tid < 65536) { int l = tid - 57344; v = pW1[(l >> 6) * 160 + 64 + (l & 63)]; }
        else if (tid < 69632) { int l = tid - 65536; v = pW1[(l >> 5) * 160 + 128 + (l & 31)]; }
        else if (tid < 71680) v = eW1[tid - 69632];
        else if (tid < 73728) v = eW2[tid - 71680];
        else                  v = pW2[tid - 73728];
        w16[tid] = (_Float16)v;
    }
    int stride = gridDim.x * 256;
    const int NV = Nn * 128 / 4;
    for (int i = tid; i < NV; i += stride) {
        float4 v = ((const float4*)x)[i];
        f16x4 h = {(_Float16)v.x, (_Float16)v.y, (_Float16)v.z, (_Float16)v.w};
        ((f16x4*)x16)[i] = h;
    }
}

// ---------------- CSR build ----------------
__global__ __launch_bounds__(256) void hist_kernel(const int* __restrict__ dst,
                                                   unsigned* __restrict__ deg) {
    int i = blockIdx.x * 256 + threadIdx.x;
    if (i < Ee) atomicAdd(&deg[dst[i]], 1u);
}

__global__ __launch_bounds__(1024) void scan_kernel(const unsigned* __restrict__ deg,
                                                    int* __restrict__ rowptr,
                                                    int* __restrict__ cursor) {
    __shared__ unsigned ssum[1024];
    int t = threadIdx.x;
    const int CH = (Nn + 1023) / 1024;
    int beg = t * CH;
    int end = min(beg + CH, Nn);
    unsigned s = 0;
    for (int i = beg; i < end; ++i) s += deg[i];
    ssum[t] = s;
    __syncthreads();
    for (int off = 1; off < 1024; off <<= 1) {
        unsigned v = (t >= off) ? ssum[t - off] : 0u;
        __syncthreads();
        ssum[t] += v;
        __syncthreads();
    }
    unsigned run = ssum[t] - s;
    for (int i = beg; i < end; ++i) {
        rowptr[i] = (int)run;
        cursor[i] = (int)run;
        run += deg[i];
    }
    if (t == 1023) rowptr[Nn] = (int)ssum[1023];
}

__global__ __launch_bounds__(256) void scatter_kernel(const int* __restrict__ src,
                                                      const int* __restrict__ dst,
                                                      int* __restrict__ cursor,
                                                      int* __restrict__ elist) {
    int i = blockIdx.x * 256 + threadIdx.x;
    if (i < Ee) {
        int p = atomicAdd(&cursor[dst[i]], 1);
        elist[p] = src[i];
    }
}

// ---------------- f16 mean aggregation: one wave per node, shfl-broadcast ----
__global__ __launch_bounds__(256) void aggregate16_kernel(const _Float16* __restrict__ feat,
                                                          const int* __restrict__ rowptr,
                                                          const int* __restrict__ elist,
                                                          _Float16* __restrict__ outp) {
    int node = (blockIdx.x * 256 + threadIdx.x) >> 6;
    int lane = threadIdx.x & 63;
    if (node >= Nn) return;
    int beg = rowptr[node], end = rowptr[node + 1];
    float ax = 0.f, ay = 0.f;
    for (int c0 = beg; c0 < end; c0 += 64) {
        int n = min(64, end - c0);
        int se = (lane < n) ? elist[c0 + lane] : 0;
        int j = 0;
        for (; j + 3 < n; j += 4) {
            int s0 = __shfl(se, j), s1 = __shfl(se, j + 1);
            int s2 = __shfl(se, j + 2), s3 = __shfl(se, j + 3);
            f16x2 v0 = *(const f16x2*)(feat + (size_t)s0 * 128 + 2 * lane);
            f16x2 v1 = *(const f16x2*)(feat + (size_t)s1 * 128 + 2 * lane);
            f16x2 v2 = *(const f16x2*)(feat + (size_t)s2 * 128 + 2 * lane);
            f16x2 v3 = *(const f16x2*)(feat + (size_t)s3 * 128 + 2 * lane);
            ax += (float)v0.x + (float)v1.x + (float)v2.x + (float)v3.x;
            ay += (float)v0.y + (float)v1.y + (float)v2.y + (float)v3.y;
        }
        for (; j < n; ++j) {
            int s0 = __shfl(se, j);
            f16x2 v0 = *(const f16x2*)(feat + (size_t)s0 * 128 + 2 * lane);
            ax += (float)v0.x; ay += (float)v0.y;
        }
    }
    float inv = 1.0f / fmaxf((float)(end - beg), 1.0f);
    f16x2 r = {(_Float16)(ax * inv), (_Float16)(ay * inv)};
    *(f16x2*)(outp + (size_t)node * 128 + 2 * lane) = r;
}

// ---------------- dense SAGE via MFMA: out16 = act(A1@W1^T + A2@W2^T + lb) ----
// block = 4 waves; wave handles 16 rows x NOUT. K = 128. No LDS.
template<int NOUT, bool BNRELU>
__global__ __launch_bounds__(256) void dense16_kernel(
    const _Float16* __restrict__ A1, const _Float16* __restrict__ A2,
    const _Float16* __restrict__ W1, const _Float16* __restrict__ W2,
    const float* __restrict__ lb,
    const float* __restrict__ bng, const float* __restrict__ bnb,
    const float* __restrict__ bnm, const float* __restrict__ bnv,
    _Float16* __restrict__ out) {
    const int t = threadIdx.x;
    const int w = t >> 6, lane = t & 63;
    const int lrow = lane & 15, lq = lane >> 4;
    const int row0 = blockIdx.x * 64 + w * 16;
    const int ld = min(row0 + lrow, Nn - 1);

    f16x8 a1[4], a2[4];
#pragma unroll
    for (int i = 0; i < 4; ++i) {
        a1[i] = *(const f16x8*)(A1 + (size_t)ld * 128 + i * 32 + lq * 8);
        a2[i] = *(const f16x8*)(A2 + (size_t)ld * 128 + i * 32 + lq * 8);
    }
#pragma unroll
    for (int nt = 0; nt < NOUT / 16; ++nt) {
        const _Float16* w1r = W1 + (size_t)(nt * 16 + lrow) * 128;
        const _Float16* w2r = W2 + (size_t)(nt * 16 + lrow) * 128;
        f32x4 c = {0.f, 0.f, 0.f, 0.f};
#pragma unroll
        for (int i = 0; i < 4; ++i) {
            c = __builtin_amdgcn_mfma_f32_16x16x32_f16(a1[i], *(const f16x8*)(w1r + i * 32 + lq * 8), c, 0, 0, 0);
            c = __builtin_amdgcn_mfma_f32_16x16x32_f16(a2[i], *(const f16x8*)(w2r + i * 32 + lq * 8), c, 0, 0, 0);
        }
        int cc = nt * 16 + lrow;
        float s, h;
        if constexpr (BNRELU) {
            s = bng[cc] * rsqrtf(bnv[cc] + EPSf);
            h = (lb[cc] - bnm[cc]) * s + bnb[cc];
        } else { s = 1.f; h = lb[cc]; }
#pragma unroll
        for (int r = 0; r < 4; ++r) {
            int gr = row0 + lq * 4 + r;
            if (gr < Nn) {
                float v = c[r] * s + h;
                if constexpr (BNRELU) v = fmaxf(v, 0.f);
                out[(size_t)gr * NOUT + cc] = (_Float16)v;
            }
        }
    }
}

// ---------------- proj via MFMA: Za = z@W1a^T, Zb = z@W1b^T (K=64, NOUT=128) --
__global__ __launch_bounds__(256) void proj16_kernel(const _Float16* __restrict__ z,
                                                     const _Float16* __restrict__ W1a,
                                                     const _Float16* __restrict__ W1b,
                                                     _Float16* __restrict__ Za,
                                                     _Float16* __restrict__ Zb) {
    const int t = threadIdx.x;
    const int w = t >> 6, lane = t & 63;
    const int lrow = lane & 15, lq = lane >> 4;
    const int row0 = blockIdx.x * 64 + w * 16;
    const int ld = min(row0 + lrow, Nn - 1);
    f16x8 a[2];
#pragma unroll
    for (int i = 0; i < 2; ++i)
        a[i] = *(const f16x8*)(z + (size_t)ld * 64 + i * 32 + lq * 8);
#pragma unroll
    for (int half = 0; half < 2; ++half) {
        const _Float16* W = half ? W1b : W1a;
        _Float16* O = half ? Zb : Za;
#pragma unroll
        for (int nt = 0; nt < 8; ++nt) {
            const _Float16* wr = W + (size_t)(nt * 16 + lrow) * 64;
            f32x4 c = {0.f, 0.f, 0.f, 0.f};
            c = __builtin_amdgcn_mfma_f32_16x16x32_f16(a[0], *(const f16x8*)(wr + 0  + lq * 8), c, 0, 0, 0);
            c = __builtin_amdgcn_mfma_f32_16x16x32_f16(a[1], *(const f16x8*)(wr + 32 + lq * 8), c, 0, 0, 0);
            int cc = nt * 16 + lrow;
#pragma unroll
            for (int r = 0; r < 4; ++r) {
                int gr = row0 + lq * 4 + r;
                if (gr < Nn) O[(size_t)gr * 128 + cc] = (_Float16)c[r];
            }
        }
    }
}

// ---------------- fused per-edge predictor: f16 MFMA, weights from global ----
#define EPB 64
// LDS: BN consts (608 f32 = 2432 B) | E1 [64][72] | E2 [64][40] | U1 [64][136]
#define oBN  0
#define oE1  2432
#define oE2  11648
#define oU1  16768
#define SMEM_BYTES 34176

__global__ __launch_bounds__(256) void edge_kernel(
    const int* __restrict__ pe,
    const float* __restrict__ ef,
    const _Float16* __restrict__ Za,
    const _Float16* __restrict__ Zb,
    const _Float16* __restrict__ w16,
    const float* __restrict__ eb1,
    const float* __restrict__ ebng, const float* __restrict__ ebnb,
    const float* __restrict__ ebnm, const float* __restrict__ ebnv,
    const float* __restrict__ eb2,
    const float* __restrict__ pb1,
    const float* __restrict__ p1g, const float* __restrict__ p1b,
    const float* __restrict__ p1m, const float* __restrict__ p1v,
    const float* __restrict__ pb2,
    const float* __restrict__ p2g, const float* __restrict__ p2b,
    const float* __restrict__ p2m, const float* __restrict__ p2v,
    const float* __restrict__ pW3, const float* __restrict__ pb3,
    float* __restrict__ out) {
    __shared__ __align__(16) unsigned char smem[SMEM_BYTES];
    float* BN   = (float*)(smem + oBN);
    float* bn1s = BN;        float* bn1h = BN + 64;
    float* bn2s = BN + 128;  float* bn2h = BN + 256;
    float* bn3s = BN + 384;  float* bn3h = BN + 448;
    float* sEb2 = BN + 512;  float* sWp3 = BN + 544;
    _Float16* E1 = (_Float16*)(smem + oE1);
    _Float16* E2 = (_Float16*)(smem + oE2);
    _Float16* U1 = (_Float16*)(smem + oU1);
    _Float16* U2 = (_Float16*)(smem + oE1);   // alias: E1 dead after P3

    const _Float16* We1 = w16 + oWe1;
    const _Float16* We2 = w16 + oWe2;
    const _Float16* W1c = w16 + oW1c;
    const _Float16* Wp2 = w16 + oWp2;

    const int t = threadIdx.x;
    const int base = blockIdx.x * EPB;
    const int lane = t & 63;
    const int w = t >> 6;
    const int m0 = w * 16;
    const int lrow = lane & 15;
    const int lq = lane >> 4;

    // ---- BN const staging ----
    if (t < 64) {
        sWp3[t] = pW3[t];
        float s = ebng[t] * rsqrtf(ebnv[t] + EPSf);
        bn1s[t] = s; bn1h[t] = (eb1[t] - ebnm[t]) * s + ebnb[t];
    } else if (t < 192) {
        int c = t - 64;
        float s = p1g[c] * rsqrtf(p1v[c] + EPSf);
        bn2s[c] = s; bn2h[c] = (pb1[c] - p1m[c]) * s + p1b[c];
    } else {
        int c = t - 192;
        float s = p2g[c] * rsqrtf(p2v[c] + EPSf);
        bn3s[c] = s; bn3h[c] = (pb2[c] - p2m[c]) * s + p2b[c];
    }
    if (t < 32) sEb2[t] = eb2[t];

    // ---- wave-private gather: U1[e][:] = Za[a_e] + Zb[b_e]  (f16) ----
#pragma unroll 4
    for (int i = 0; i < 16; ++i) {
        int e = m0 + i;
        int ai = pe[base + e];
        int bi = pe[Pp + base + e];
        f16x2 va = *(const f16x2*)(Za + (size_t)ai * 128 + 2 * lane);
        f16x2 vb = *(const f16x2*)(Zb + (size_t)bi * 128 + 2 * lane);
        f16x2 h = {(_Float16)((float)va.x + (float)vb.x),
                   (_Float16)((float)va.y + (float)vb.y)};
        *(f16x2*)(U1 + e * 136 + 2 * lane) = h;
    }
    __syncthreads();

    // ---- P2: e1 = relu(bn(ef @ eW1^T)), [16x32]@[32x64]; ef A-frag from global
    {
        const float* src = ef + (size_t)(base + m0 + lrow) * 32 + lq * 8;
        float4 v0 = ld4(src), v1 = ld4(src + 4);
        f16x8 a = {(_Float16)v0.x, (_Float16)v0.y, (_Float16)v0.z, (_Float16)v0.w,
                   (_Float16)v1.x, (_Float16)v1.y, (_Float16)v1.z, (_Float16)v1.w};
#pragma unroll
        for (int nt = 0; nt < 4; ++nt) {
            f16x8 b = *(const f16x8*)(We1 + (nt * 16 + lrow) * 32 + lq * 8);
            f32x4 c = {0.f, 0.f, 0.f, 0.f};
            c = __builtin_amdgcn_mfma_f32_16x16x32_f16(a, b, c, 0, 0, 0);
            int cc = nt * 16 + lrow;
            float s = bn1s[cc], h = bn1h[cc];
#pragma unroll
            for (int r = 0; r < 4; ++r) {
                int rr = m0 + lq * 4 + r;
                E1[rr * 72 + cc] = (_Float16)fmaxf(c[r] * s + h, 0.f);
            }
        }
    }
    // ---- P3: e2 = e1 @ eW2^T + eb2, [16x64]@[64x32]
    {
        f16x8 a0 = *(const f16x8*)(E1 + (m0 + lrow) * 72 + lq * 8);
        f16x8 a1 = *(const f16x8*)(E1 + (m0 + lrow) * 72 + 32 + lq * 8);
#pragma unroll
        for (int nt = 0; nt < 2; ++nt) {
            f16x8 b0 = *(const f16x8*)(We2 + (nt * 16 + lrow) * 64 + lq * 8);
            f16x8 b1 = *(const f16x8*)(We2 + (nt * 16 + lrow) * 64 + 32 + lq * 8);
            f32x4 c = {0.f, 0.f, 0.f, 0.f};
            c = __builtin_amdgcn_mfma_f32_16x16x32_f16(a0, b0, c, 0, 0, 0);
            c = __builtin_amdgcn_mfma_f32_16x16x32_f16(a1, b1, c, 0, 0, 0);
            int cc = nt * 16 + lrow;
            float bias = sEb2[cc];
#pragma unroll
            for (int r = 0; r < 4; ++r) {
                int rr = m0 + lq * 4 + r;
                E2[rr * 40 + cc] = (_Float16)(c[r] + bias);
            }
        }
    }
    // ---- P4b: u1 = relu(bn1(gather + e2 @ W1c^T)), [16x32]@[32x128]
    {
        f16x8 a = *(const f16x8*)(E2 + (m0 + lrow) * 40 + lq * 8);
#pragma unroll
        for (int nt = 0; nt < 8; ++nt) {
            f16x8 b = *(const f16x8*)(W1c + (nt * 16 + lrow) * 32 + lq * 8);
            f32x4 c = {0.f, 0.f, 0.f, 0.f};
            c = __builtin_amdgcn_mfma_f32_16x16x32_f16(a, b, c, 0, 0, 0);
            int cc = nt * 16 + lrow;
            float s = bn2s[cc], h = bn2h[cc];
#pragma unroll
            for (int r = 0; r < 4; ++r) {
                int rr = m0 + lq * 4 + r;
                float g = (float)U1[rr * 136 + cc];
                U1[rr * 136 + cc] = (_Float16)fmaxf((c[r] + g) * s + h, 0.f);
            }
        }
    }
    // ---- P6: u2 = relu(bn2(u1 @ pW2^T)), [16x128]@[128x64]
    {
        f16x8 a0 = *(const f16x8*)(U1 + (m0 + lrow) * 136 + 0  + lq * 8);
        f16x8 a1 = *(const f16x8*)(U1 + (m0 + lrow) * 136 + 32 + lq * 8);
        f16x8 a2 = *(const f16x8*)(U1 + (m0 + lrow) * 136 + 64 + lq * 8);
        f16x8 a3 = *(const f16x8*)(U1 + (m0 + lrow) * 136 + 96 + lq * 8);
#pragma unroll
        for (int nt = 0; nt < 4; ++nt) {
            const _Float16* wr = Wp2 + (nt * 16 + lrow) * 128 + lq * 8;
            f32x4 c = {0.f, 0.f, 0.f, 0.f};
            c = __builtin_amdgcn_mfma_f32_16x16x32_f16(a0, *(const f16x8*)(wr + 0),  c, 0, 0, 0);
            c = __builtin_amdgcn_mfma_f32_16x16x32_f16(a1, *(const f16x8*)(wr + 32), c, 0, 0, 0);
            c = __builtin_amdgcn_mfma_f32_16x16x32_f16(a2, *(const f16x8*)(wr + 64), c, 0, 0, 0);
            c = __builtin_amdgcn_mfma_f32_16x16x32_f16(a3, *(const f16x8*)(wr + 96), c, 0, 0, 0);
            int cc = nt * 16 + lrow;
            float s = bn3s[cc], h = bn3h[cc];
#pragma unroll
            for (int r = 0; r < 4; ++r) {
                int rr = m0 + lq * 4 + r;
                U2[rr * 72 + cc] = (_Float16)fmaxf(c[r] * s + h, 0.f);
            }
        }
    }
    // ---- P7: out = u2 @ pW3 + pb3 (4 lanes per edge)
    {
        int e = m0 + (lane >> 2);
        int c0 = (lane & 3) * 16;
        f16x8 u0 = *(const f16x8*)(U2 + e * 72 + c0);
        f16x8 u1 = *(const f16x8*)(U2 + e * 72 + c0 + 8);
        float acc = 0.f;
#pragma unroll
        for (int j = 0; j < 8; ++j) acc += (float)u0[j] * sWp3[c0 + j];
#pragma unroll
        for (int j = 0; j < 8; ++j) acc += (float)u1[j] * sWp3[c0 + 8 + j];
        acc += __shfl_xor(acc, 1);
        acc += __shfl_xor(acc, 2);
        if ((lane & 3) == 0) out[base + e] = acc + pb3[0];
    }
}

// ---------------- launch ----------------
extern "C" void kernel_launch(void* const* d_in, const int* in_sizes, int n_in,
                              void* d_out, int out_size, void* d_ws, size_t ws_size,
                              hipStream_t stream) {
    const float* x    = (const float*)d_in[0];
    const int*   eidx = (const int*)d_in[1];
    const int*   pe   = (const int*)d_in[2];
    const float* ef   = (const float*)d_in[3];
    const float* s1Wl = (const float*)d_in[4];
    const float* s1bl = (const float*)d_in[5];
    const float* s1Wr = (const float*)d_in[6];
    const float* bn1g = (const float*)d_in[7];
    const float* bn1b = (const float*)d_in[8];
    const float* bn1m = (const float*)d_in[9];
    const float* bn1v = (const float*)d_in[10];
    const float* s2Wl = (const float*)d_in[11];
    const float* s2bl = (const float*)d_in[12];
    const float* s2Wr = (const float*)d_in[13];
    const float* eW1  = (const float*)d_in[14];
    const float* eb1  = (const float*)d_in[15];
    const float* ebng = (const float*)d_in[16];
    const float* ebnb = (const float*)d_in[17];
    const float* ebnm = (const float*)d_in[18];
    const float* ebnv = (const float*)d_in[19];
    const float* eW2  = (const float*)d_in[20];
    const float* eb2  = (const float*)d_in[21];
    const float* pW1  = (const float*)d_in[22];
    const float* pb1  = (const float*)d_in[23];
    const float* p1g  = (const float*)d_in[24];
    const float* p1b  = (const float*)d_in[25];
    const float* p1m  = (const float*)d_in[26];
    const float* p1v  = (const float*)d_in[27];
    const float* pW2  = (const float*)d_in[28];
    const float* pb2  = (const float*)d_in[29];
    const float* p2g  = (const float*)d_in[30];
    const float* p2b  = (const float*)d_in[31];
    const float* p2m  = (const float*)d_in[32];
    const float* p2v  = (const float*)d_in[33];
    const float* pW3  = (const float*)d_in[34];
    const float* pb3  = (const float*)d_in[35];
    float* out = (float*)d_out;

    char* w = (char*)d_ws;
    auto carve = [&](size_t bytes) {
        char* p = w;
        w += (bytes + 255) & ~(size_t)255;
        return p;
    };
    unsigned*  deg    = (unsigned*)carve((size_t)Nn * 4);
    int*       rowptr = (int*)carve((size_t)(Nn + 1) * 4);
    int*       cursor = (int*)carve((size_t)Nn * 4);
    int*       elist  = (int*)carve((size_t)Ee * 4);
    _Float16*  w16    = (_Float16*)carve((size_t)W16_TOTAL * 2);
    _Float16*  bufX   = (_Float16*)carve((size_t)Nn * 128 * 2);  // x16, later Za
    _Float16*  bufH   = (_Float16*)carve((size_t)Nn * 128 * 2);  // h16, later Zb
    _Float16*  bufA   = (_Float16*)carve((size_t)Nn * 128 * 2);  // aggregation
    _Float16*  bufZ   = (_Float16*)carve((size_t)Nn * 64 * 2);   // z16

    const int* e_src = eidx;
    const int* e_dst = eidx + Ee;

    hipMemsetAsync(deg, 0, (size_t)Nn * 4, stream);
    prep_kernel<<<800, 256, 0, stream>>>(x, s1Wl, s1Wr, s2Wl, s2Wr, pW1, eW1, eW2, pW2,
                                         w16, bufX);
    hist_kernel<<<(Ee + 255) / 256, 256, 0, stream>>>(e_dst, deg);
    scan_kernel<<<1, 1024, 0, stream>>>(deg, rowptr, cursor);
    scatter_kernel<<<(Ee + 255) / 256, 256, 0, stream>>>(e_src, e_dst, cursor, elist);

    // SAGE layer 1
    aggregate16_kernel<<<Nn / 4, 256, 0, stream>>>(bufX, rowptr, elist, bufA);
    dense16_kernel<128, true><<<(Nn + 63) / 64, 256, 0, stream>>>(
        bufA, bufX, w16 + oW1l, w16 + oW1r, s1bl, bn1g, bn1b, bn1m, bn1v, bufH);

    // SAGE layer 2
    aggregate16_kernel<<<Nn / 4, 256, 0, stream>>>(bufH, rowptr, elist, bufA);
    dense16_kernel<64, false><<<(Nn + 63) / 64, 256, 0, stream>>>(
        bufA, bufH, w16 + oW2l, w16 + oW2r, s2bl, nullptr, nullptr, nullptr, nullptr, bufZ);

    // node-side projection of predictor W1 (Za into bufX, Zb into bufH)
    proj16_kernel<<<(Nn + 63) / 64, 256, 0, stream>>>(bufZ, w16 + oW1a, w16 + oW1b, bufX, bufH);

    // fused per-edge predictor
    edge_kernel<<<Pp / EPB, 256, 0, stream>>>(
        pe, ef, bufX, bufH, w16,
        eb1, ebng, ebnb, ebnm, ebnv, eb2,
        pb1, p1g, p1b, p1m, p1v,
        pb2, p2g, p2b, p2m, p2v,
        pW3, pb3, out);
}

// Round 4
// 1134.378 us; speedup vs baseline: 2.8255x; 1.0115x over previous
//
#include <hip/hip_runtime.h>

#define Nn 100000
#define Ee 1600000
#define Pp 1000000
#define EPSf 1e-5f

typedef _Float16 f16x8 __attribute__((ext_vector_type(8)));
typedef _Float16 f16x4 __attribute__((ext_vector_type(4)));
typedef _Float16 f16x2 __attribute__((ext_vector_type(2)));
typedef float f32x4 __attribute__((ext_vector_type(4)));

__device__ __forceinline__ float4 ld4(const float* p) { return *(const float4*)p; }

// f16 weight arena offsets (elements)
#define oW1l 0        // 128x128
#define oW1r 16384    // 128x128
#define oW2l 32768    // 64x128
#define oW2r 40960    // 64x128
#define oW1a 49152    // 128x64   (pW1 cols 0..63)
#define oW1b 57344    // 128x64   (pW1 cols 64..127)
#define oW1c 65536    // 128x32   (pW1 cols 128..159)
#define oWe1 69632    // 64x32
#define oWe2 71680    // 32x64
#define oWp2 73728    // 64x128
#define W16_TOTAL 81920

// BN-const arena layout (floats)
//  [0:64) bn1s | [64:128) bn1h | [128:256) bn2s | [256:384) bn2h
//  [384:448) bn3s | [448:512) bn3h | [512:544) eb2 | [544:608) pW3
#define BN_TOTAL 608

// ---------------- prep: f32 -> f16 weights/x + BN const folding ----------------
__global__ __launch_bounds__(256) void prep_kernel(
    const float* __restrict__ x,
    const float* __restrict__ s1Wl, const float* __restrict__ s1Wr,
    const float* __restrict__ s2Wl, const float* __restrict__ s2Wr,
    const float* __restrict__ pW1,  const float* __restrict__ eW1,
    const float* __restrict__ eW2,  const float* __restrict__ pW2,
    const float* __restrict__ eb1,
    const float* __restrict__ ebng, const float* __restrict__ ebnb,
    const float* __restrict__ ebnm, const float* __restrict__ ebnv,
    const float* __restrict__ eb2,
    const float* __restrict__ pb1,
    const float* __restrict__ p1g, const float* __restrict__ p1b,
    const float* __restrict__ p1m, const float* __restrict__ p1v,
    const float* __restrict__ pb2,
    const float* __restrict__ p2g, const float* __restrict__ p2b,
    const float* __restrict__ p2m, const float* __restrict__ p2v,
    const float* __restrict__ pW3,
    _Float16* __restrict__ w16, float* __restrict__ bnA,
    _Float16* __restrict__ x16) {
    int tid = blockIdx.x * 256 + threadIdx.x;
    if (tid < W16_TOTAL) {
        float v;
        if (tid < 16384)      v = s1Wl[tid];
        else if (tid < 32768) v = s1Wr[tid - 16384];
        else if (tid < 40960) v = s2Wl[tid - 32768];
        else if (tid < 49152) v = s2Wr[tid - 40960];
        else if (tid < 57344) { int l = tid - 49152; v = pW1[(l >> 6) * 160 + (l & 63)]; }
        else if (tid < 65536) { int l = tid - 57344; v = pW1[(l >> 6) * 160 + 64 + (l & 63)]; }
        else if (tid < 69632) { int l = tid - 65536; v = pW1[(l >> 5) * 160 + 128 + (l & 31)]; }
        else if (tid < 71680) v = eW1[tid - 69632];
        else if (tid < 73728) v = eW2[tid - 71680];
        else                  v = pW2[tid - 73728];
        w16[tid] = (_Float16)v;
    } else if (tid < W16_TOTAL + BN_TOTAL) {
        int b = tid - W16_TOTAL;
        float v;
        if (b < 64)       v = ebng[b] * rsqrtf(ebnv[b] + EPSf);
        else if (b < 128) { int c = b - 64;  float s = ebng[c] * rsqrtf(ebnv[c] + EPSf);
                            v = (eb1[c] - ebnm[c]) * s + ebnb[c]; }
        else if (b < 256) { int c = b - 128; v = p1g[c] * rsqrtf(p1v[c] + EPSf); }
        else if (b < 384) { int c = b - 256; float s = p1g[c] * rsqrtf(p1v[c] + EPSf);
                            v = (pb1[c] - p1m[c]) * s + p1b[c]; }
        else if (b < 448) { int c = b - 384; v = p2g[c] * rsqrtf(p2v[c] + EPSf); }
        else if (b < 512) { int c = b - 448; float s = p2g[c] * rsqrtf(p2v[c] + EPSf);
                            v = (pb2[c] - p2m[c]) * s + p2b[c]; }
        else if (b < 544) v = eb2[b - 512];
        else              v = pW3[b - 544];
        bnA[b] = v;
    }
    int stride = gridDim.x * 256;
    const int NV = Nn * 128 / 4;
    for (int i = tid; i < NV; i += stride) {
        float4 v = ((const float4*)x)[i];
        f16x4 h = {(_Float16)v.x, (_Float16)v.y, (_Float16)v.z, (_Float16)v.w};
        ((f16x4*)x16)[i] = h;
    }
}

// ---------------- CSR build ----------------
__global__ __launch_bounds__(256) void hist_kernel(const int* __restrict__ dst,
                                                   unsigned* __restrict__ deg) {
    int i = blockIdx.x * 256 + threadIdx.x;
    if (i < Ee) atomicAdd(&deg[dst[i]], 1u);
}

__global__ __launch_bounds__(1024) void scan_kernel(const unsigned* __restrict__ deg,
                                                    int* __restrict__ rowptr,
                                                    int* __restrict__ cursor) {
    __shared__ unsigned ssum[1024];
    int t = threadIdx.x;
    const int CH = (Nn + 1023) / 1024;
    int beg = t * CH;
    int end = min(beg + CH, Nn);
    unsigned s = 0;
    for (int i = beg; i < end; ++i) s += deg[i];
    ssum[t] = s;
    __syncthreads();
    for (int off = 1; off < 1024; off <<= 1) {
        unsigned v = (t >= off) ? ssum[t - off] : 0u;
        __syncthreads();
        ssum[t] += v;
        __syncthreads();
    }
    unsigned run = ssum[t] - s;
    for (int i = beg; i < end; ++i) {
        rowptr[i] = (int)run;
        cursor[i] = (int)run;
        run += deg[i];
    }
    if (t == 1023) rowptr[Nn] = (int)ssum[1023];
}

__global__ __launch_bounds__(256) void scatter_kernel(const int* __restrict__ src,
                                                      const int* __restrict__ dst,
                                                      int* __restrict__ cursor,
                                                      int* __restrict__ elist) {
    int i = blockIdx.x * 256 + threadIdx.x;
    if (i < Ee) {
        int p = atomicAdd(&cursor[dst[i]], 1);
        elist[p] = src[i];
    }
}

// ---------------- f16 mean aggregation: wave/node, 4 rows per load-inst ------
// lane = (r,c): r = lane>>4 (neighbor-row offset), c = lane&15 (16B col seg).
__global__ __launch_bounds__(256, 8) void aggregate16_kernel(
    const _Float16* __restrict__ feat,
    const int* __restrict__ rowptr,
    const int* __restrict__ elist,
    _Float16* __restrict__ outp) {
    int node = (blockIdx.x * 256 + threadIdx.x) >> 6;
    int lane = threadIdx.x & 63;
    if (node >= Nn) return;
    const int r = lane >> 4, c = lane & 15;
    int beg = rowptr[node], end = rowptr[node + 1];
    int n = end - beg;
    float acc[8];
#pragma unroll
    for (int k = 0; k < 8; ++k) acc[k] = 0.f;
    for (int c0 = 0; c0 < n; c0 += 64) {
        int m = min(64, n - c0);
        int se = (lane < m) ? elist[beg + c0 + lane] : 0;
        int iters = (m + 3) >> 2;
#pragma unroll 2
        for (int i = 0; i < iters; ++i) {
            int j = i * 4 + r;
            int s = __shfl(se, j);
            if (j < m) {
                f16x8 v = *(const f16x8*)(feat + (size_t)s * 128 + c * 8);
#pragma unroll
                for (int k = 0; k < 8; ++k) acc[k] += (float)v[k];
            }
        }
    }
#pragma unroll
    for (int k = 0; k < 8; ++k) {
        acc[k] += __shfl_xor(acc[k], 16);
        acc[k] += __shfl_xor(acc[k], 32);
    }
    if (r == 0) {
        float inv = 1.0f / fmaxf((float)n, 1.0f);
        f16x8 o;
#pragma unroll
        for (int k = 0; k < 8; ++k) o[k] = (_Float16)(acc[k] * inv);
        *(f16x8*)(outp + (size_t)node * 128 + c * 8) = o;
    }
}

// ---------------- dense SAGE via MFMA (register-only) ----------------
template<int NOUT, bool BNRELU>
__global__ __launch_bounds__(256) void dense16_kernel(
    const _Float16* __restrict__ A1, const _Float16* __restrict__ A2,
    const _Float16* __restrict__ W1, const _Float16* __restrict__ W2,
    const float* __restrict__ lb,
    const float* __restrict__ bng, const float* __restrict__ bnb,
    const float* __restrict__ bnm, const float* __restrict__ bnv,
    _Float16* __restrict__ out) {
    const int t = threadIdx.x;
    const int w = t >> 6, lane = t & 63;
    const int lrow = lane & 15, lq = lane >> 4;
    const int row0 = blockIdx.x * 64 + w * 16;
    const int ld = min(row0 + lrow, Nn - 1);

    f16x8 a1[4], a2[4];
#pragma unroll
    for (int i = 0; i < 4; ++i) {
        a1[i] = *(const f16x8*)(A1 + (size_t)ld * 128 + i * 32 + lq * 8);
        a2[i] = *(const f16x8*)(A2 + (size_t)ld * 128 + i * 32 + lq * 8);
    }
#pragma unroll
    for (int nt = 0; nt < NOUT / 16; ++nt) {
        const _Float16* w1r = W1 + (size_t)(nt * 16 + lrow) * 128;
        const _Float16* w2r = W2 + (size_t)(nt * 16 + lrow) * 128;
        f32x4 c = {0.f, 0.f, 0.f, 0.f};
#pragma unroll
        for (int i = 0; i < 4; ++i) {
            c = __builtin_amdgcn_mfma_f32_16x16x32_f16(a1[i], *(const f16x8*)(w1r + i * 32 + lq * 8), c, 0, 0, 0);
            c = __builtin_amdgcn_mfma_f32_16x16x32_f16(a2[i], *(const f16x8*)(w2r + i * 32 + lq * 8), c, 0, 0, 0);
        }
        int cc = nt * 16 + lrow;
        float s, h;
        if constexpr (BNRELU) {
            s = bng[cc] * rsqrtf(bnv[cc] + EPSf);
            h = (lb[cc] - bnm[cc]) * s + bnb[cc];
        } else { s = 1.f; h = lb[cc]; }
#pragma unroll
        for (int r = 0; r < 4; ++r) {
            int gr = row0 + lq * 4 + r;
            if (gr < Nn) {
                float v = c[r] * s + h;
                if constexpr (BNRELU) v = fmaxf(v, 0.f);
                out[(size_t)gr * NOUT + cc] = (_Float16)v;
            }
        }
    }
}

// ---------------- proj via MFMA ----------------
__global__ __launch_bounds__(256) void proj16_kernel(const _Float16* __restrict__ z,
                                                     const _Float16* __restrict__ W1a,
                                                     const _Float16* __restrict__ W1b,
                                                     _Float16* __restrict__ Za,
                                                     _Float16* __restrict__ Zb) {
    const int t = threadIdx.x;
    const int w = t >> 6, lane = t & 63;
    const int lrow = lane & 15, lq = lane >> 4;
    const int row0 = blockIdx.x * 64 + w * 16;
    const int ld = min(row0 + lrow, Nn - 1);
    f16x8 a[2];
#pragma unroll
    for (int i = 0; i < 2; ++i)
        a[i] = *(const f16x8*)(z + (size_t)ld * 64 + i * 32 + lq * 8);
#pragma unroll
    for (int half = 0; half < 2; ++half) {
        const _Float16* W = half ? W1b : W1a;
        _Float16* O = half ? Zb : Za;
#pragma unroll
        for (int nt = 0; nt < 8; ++nt) {
            const _Float16* wr = W + (size_t)(nt * 16 + lrow) * 64;
            f32x4 c = {0.f, 0.f, 0.f, 0.f};
            c = __builtin_amdgcn_mfma_f32_16x16x32_f16(a[0], *(const f16x8*)(wr + 0  + lq * 8), c, 0, 0, 0);
            c = __builtin_amdgcn_mfma_f32_16x16x32_f16(a[1], *(const f16x8*)(wr + 32 + lq * 8), c, 0, 0, 0);
            int cc = nt * 16 + lrow;
#pragma unroll
            for (int r = 0; r < 4; ++r) {
                int gr = row0 + lq * 4 + r;
                if (gr < Nn) O[(size_t)gr * 128 + cc] = (_Float16)c[r];
            }
        }
    }
}

// ---------------- fused per-edge predictor: barrier-free, BN from global ----
#define EPB 64
#define oE1  0       // e1 f16 [64][72]  9216 B  (aliased by U2)
#define oE2  9216    // e2 f16 [64][40]  5120 B
#define oU1  14336   // u1 f16 [64][136] 17408 B
#define SMEM_BYTES 31744

__global__ __launch_bounds__(256, 5) void edge_kernel(
    const int* __restrict__ pe,
    const float* __restrict__ ef,
    const _Float16* __restrict__ Za,
    const _Float16* __restrict__ Zb,
    const _Float16* __restrict__ w16,
    const float* __restrict__ bnA,
    const float* __restrict__ pb3,
    float* __restrict__ out) {
    __shared__ __align__(16) unsigned char smem[SMEM_BYTES];
    _Float16* E1 = (_Float16*)(smem + oE1);
    _Float16* E2 = (_Float16*)(smem + oE2);
    _Float16* U1 = (_Float16*)(smem + oU1);
    _Float16* U2 = (_Float16*)(smem + oE1);   // alias: E1 dead after P3

    const _Float16* We1 = w16 + oWe1;
    const _Float16* We2 = w16 + oWe2;
    const _Float16* W1c = w16 + oW1c;
    const _Float16* Wp2 = w16 + oWp2;
    const float* bn1s = bnA;        const float* bn1h = bnA + 64;
    const float* bn2s = bnA + 128;  const float* bn2h = bnA + 256;
    const float* bn3s = bnA + 384;  const float* bn3h = bnA + 448;
    const float* eb2g = bnA + 512;  const float* wp3g = bnA + 544;

    const int t = threadIdx.x;
    const int base = blockIdx.x * EPB;
    const int lane = t & 63;
    const int w = t >> 6;
    const int m0 = w * 16;
    const int lrow = lane & 15;
    const int lq = lane >> 4;
    const int r4 = lane >> 4;      // gather quarter
    const int c16 = lane & 15;

    // ---- issue all gather loads up front (overlap with edge-MLP MFMAs) ----
    f16x8 ga[4], gb[4];
#pragma unroll
    for (int i = 0; i < 4; ++i) {
        int e = m0 + i * 4 + r4;
        int ai = pe[base + e];
        int bi = pe[Pp + base + e];
        ga[i] = *(const f16x8*)(Za + (size_t)ai * 128 + c16 * 8);
        gb[i] = *(const f16x8*)(Zb + (size_t)bi * 128 + c16 * 8);
    }

    // ---- P2: e1 = relu(bn(ef @ eW1^T)), [16x32]@[32x64]; ef A-frag from global
    {
        const float* src = ef + (size_t)(base + m0 + lrow) * 32 + lq * 8;
        float4 v0 = ld4(src), v1 = ld4(src + 4);
        f16x8 a = {(_Float16)v0.x, (_Float16)v0.y, (_Float16)v0.z, (_Float16)v0.w,
                   (_Float16)v1.x, (_Float16)v1.y, (_Float16)v1.z, (_Float16)v1.w};
#pragma unroll
        for (int nt = 0; nt < 4; ++nt) {
            f16x8 b = *(const f16x8*)(We1 + (nt * 16 + lrow) * 32 + lq * 8);
            f32x4 c = {0.f, 0.f, 0.f, 0.f};
            c = __builtin_amdgcn_mfma_f32_16x16x32_f16(a, b, c, 0, 0, 0);
            int cc = nt * 16 + lrow;
            float s = bn1s[cc], h = bn1h[cc];
#pragma unroll
            for (int r = 0; r < 4; ++r) {
                int rr = m0 + lq * 4 + r;
                E1[rr * 72 + cc] = (_Float16)fmaxf(c[r] * s + h, 0.f);
            }
        }
    }
    // ---- combine + store gather rows into U1 ----
#pragma unroll
    for (int i = 0; i < 4; ++i) {
        int e = m0 + i * 4 + r4;
        f16x8 h = ga[i] + gb[i];
        *(f16x8*)(U1 + e * 136 + c16 * 8) = h;
    }
    // ---- P3: e2 = e1 @ eW2^T + eb2, [16x64]@[64x32]
    {
        f16x8 a0 = *(const f16x8*)(E1 + (m0 + lrow) * 72 + lq * 8);
        f16x8 a1 = *(const f16x8*)(E1 + (m0 + lrow) * 72 + 32 + lq * 8);
#pragma unroll
        for (int nt = 0; nt < 2; ++nt) {
            f16x8 b0 = *(const f16x8*)(We2 + (nt * 16 + lrow) * 64 + lq * 8);
            f16x8 b1 = *(const f16x8*)(We2 + (nt * 16 + lrow) * 64 + 32 + lq * 8);
            f32x4 c = {0.f, 0.f, 0.f, 0.f};
            c = __builtin_amdgcn_mfma_f32_16x16x32_f16(a0, b0, c, 0, 0, 0);
            c = __builtin_amdgcn_mfma_f32_16x16x32_f16(a1, b1, c, 0, 0, 0);
            int cc = nt * 16 + lrow;
            float bias = eb2g[cc];
#pragma unroll
            for (int r = 0; r < 4; ++r) {
                int rr = m0 + lq * 4 + r;
                E2[rr * 40 + cc] = (_Float16)(c[r] + bias);
            }
        }
    }
    // ---- P4b: u1 = relu(bn1(gather + e2 @ W1c^T)), [16x32]@[32x128]
    {
        f16x8 a = *(const f16x8*)(E2 + (m0 + lrow) * 40 + lq * 8);
#pragma unroll
        for (int nt = 0; nt < 8; ++nt) {
            f16x8 b = *(const f16x8*)(W1c + (nt * 16 + lrow) * 32 + lq * 8);
            f32x4 c = {0.f, 0.f, 0.f, 0.f};
            c = __builtin_amdgcn_mfma_f32_16x16x32_f16(a, b, c, 0, 0, 0);
            int cc = nt * 16 + lrow;
            float s = bn2s[cc], h = bn2h[cc];
#pragma unroll
            for (int r = 0; r < 4; ++r) {
                int rr = m0 + lq * 4 + r;
                float g = (float)U1[rr * 136 + cc];
                U1[rr * 136 + cc] = (_Float16)fmaxf((c[r] + g) * s + h, 0.f);
            }
        }
    }
    // ---- P6: u2 = relu(bn2(u1 @ pW2^T)), [16x128]@[128x64]
    {
        f16x8 a0 = *(const f16x8*)(U1 + (m0 + lrow) * 136 + 0  + lq * 8);
        f16x8 a1 = *(const f16x8*)(U1 + (m0 + lrow) * 136 + 32 + lq * 8);
        f16x8 a2 = *(const f16x8*)(U1 + (m0 + lrow) * 136 + 64 + lq * 8);
        f16x8 a3 = *(const f16x8*)(U1 + (m0 + lrow) * 136 + 96 + lq * 8);
#pragma unroll
        for (int nt = 0; nt < 4; ++nt) {
            const _Float16* wr = Wp2 + (nt * 16 + lrow) * 128 + lq * 8;
            f32x4 c = {0.f, 0.f, 0.f, 0.f};
            c = __builtin_amdgcn_mfma_f32_16x16x32_f16(a0, *(const f16x8*)(wr + 0),  c, 0, 0, 0);
            c = __builtin_amdgcn_mfma_f32_16x16x32_f16(a1, *(const f16x8*)(wr + 32), c, 0, 0, 0);
            c = __builtin_amdgcn_mfma_f32_16x16x32_f16(a2, *(const f16x8*)(wr + 64), c, 0, 0, 0);
            c = __builtin_amdgcn_mfma_f32_16x16x32_f16(a3, *(const f16x8*)(wr + 96), c, 0, 0, 0);
            int cc = nt * 16 + lrow;
            float s = bn3s[cc], h = bn3h[cc];
#pragma unroll
            for (int r = 0; r < 4; ++r) {
                int rr = m0 + lq * 4 + r;
                U2[rr * 72 + cc] = (_Float16)fmaxf(c[r] * s + h, 0.f);
            }
        }
    }
    // ---- P7: out = u2 @ pW3 + pb3 (4 lanes per edge)
    {
        int e = m0 + (lane >> 2);
        int c0 = (lane & 3) * 16;
        f16x8 u0 = *(const f16x8*)(U2 + e * 72 + c0);
        f16x8 u1 = *(const f16x8*)(U2 + e * 72 + c0 + 8);
        float acc = 0.f;
#pragma unroll
        for (int j = 0; j < 8; ++j) acc += (float)u0[j] * wp3g[c0 + j];
#pragma unroll
        for (int j = 0; j < 8; ++j) acc += (float)u1[j] * wp3g[c0 + 8 + j];
        acc += __shfl_xor(acc, 1);
        acc += __shfl_xor(acc, 2);
        if ((lane & 3) == 0) out[base + e] = acc + pb3[0];
    }
}

// ---------------- launch ----------------
extern "C" void kernel_launch(void* const* d_in, const int* in_sizes, int n_in,
                              void* d_out, int out_size, void* d_ws, size_t ws_size,
                              hipStream_t stream) {
    const float* x    = (const float*)d_in[0];
    const int*   eidx = (const int*)d_in[1];
    const int*   pe   = (const int*)d_in[2];
    const float* ef   = (const float*)d_in[3];
    const float* s1Wl = (const float*)d_in[4];
    const float* s1bl = (const float*)d_in[5];
    const float* s1Wr = (const float*)d_in[6];
    const float* bn1g = (const float*)d_in[7];
    const float* bn1b = (const float*)d_in[8];
    const float* bn1m = (const float*)d_in[9];
    const float* bn1v = (const float*)d_in[10];
    const float* s2Wl = (const float*)d_in[11];
    const float* s2bl = (const float*)d_in[12];
    const float* s2Wr = (const float*)d_in[13];
    const float* eW1  = (const float*)d_in[14];
    const float* eb1  = (const float*)d_in[15];
    const float* ebng = (const float*)d_in[16];
    const float* ebnb = (const float*)d_in[17];
    const float* ebnm = (const float*)d_in[18];
    const float* ebnv = (const float*)d_in[19];
    const float* eW2  = (const float*)d_in[20];
    const float* eb2  = (const float*)d_in[21];
    const float* pW1  = (const float*)d_in[22];
    const float* pb1  = (const float*)d_in[23];
    const float* p1g  = (const float*)d_in[24];
    const float* p1b  = (const float*)d_in[25];
    const float* p1m  = (const float*)d_in[26];
    const float* p1v  = (const float*)d_in[27];
    const float* pW2  = (const float*)d_in[28];
    const float* pb2  = (const float*)d_in[29];
    const float* p2g  = (const float*)d_in[30];
    const float* p2b  = (const float*)d_in[31];
    const float* p2m  = (const float*)d_in[32];
    const float* p2v  = (const float*)d_in[33];
    const float* pW3  = (const float*)d_in[34];
    const float* pb3  = (const float*)d_in[35];
    float* out = (float*)d_out;

    char* wk = (char*)d_ws;
    auto carve = [&](size_t bytes) {
        char* p = wk;
        wk += (bytes + 255) & ~(size_t)255;
        return p;
    };
    unsigned*  deg    = (unsigned*)carve((size_t)Nn * 4);
    int*       rowptr = (int*)carve((size_t)(Nn + 1) * 4);
    int*       cursor = (int*)carve((size_t)Nn * 4);
    int*       elist  = (int*)carve((size_t)Ee * 4);
    _Float16*  w16    = (_Float16*)carve((size_t)W16_TOTAL * 2);
    float*     bnA    = (float*)carve((size_t)BN_TOTAL * 4);
    _Float16*  bufX   = (_Float16*)carve((size_t)Nn * 128 * 2);  // x16, later Za
    _Float16*  bufH   = (_Float16*)carve((size_t)Nn * 128 * 2);  // h16, later Zb
    _Float16*  bufA   = (_Float16*)carve((size_t)Nn * 128 * 2);  // aggregation
    _Float16*  bufZ   = (_Float16*)carve((size_t)Nn * 64 * 2);   // z16

    const int* e_src = eidx;
    const int* e_dst = eidx + Ee;

    hipMemsetAsync(deg, 0, (size_t)Nn * 4, stream);
    prep_kernel<<<800, 256, 0, stream>>>(x, s1Wl, s1Wr, s2Wl, s2Wr, pW1, eW1, eW2, pW2,
                                         eb1, ebng, ebnb, ebnm, ebnv, eb2,
                                         pb1, p1g, p1b, p1m, p1v,
                                         pb2, p2g, p2b, p2m, p2v, pW3,
                                         w16, bnA, bufX);
    hist_kernel<<<(Ee + 255) / 256, 256, 0, stream>>>(e_dst, deg);
    scan_kernel<<<1, 1024, 0, stream>>>(deg, rowptr, cursor);
    scatter_kernel<<<(Ee + 255) / 256, 256, 0, stream>>>(e_src, e_dst, cursor, elist);

    // SAGE layer 1
    aggregate16_kernel<<<Nn / 4, 256, 0, stream>>>(bufX, rowptr, elist, bufA);
    dense16_kernel<128, true><<<(Nn + 63) / 64, 256, 0, stream>>>(
        bufA, bufX, w16 + oW1l, w16 + oW1r, s1bl, bn1g, bn1b, bn1m, bn1v, bufH);

    // SAGE layer 2
    aggregate16_kernel<<<Nn / 4, 256, 0, stream>>>(bufH, rowptr, elist, bufA);
    dense16_kernel<64, false><<<(Nn + 63) / 64, 256, 0, stream>>>(
        bufA, bufH, w16 + oW2l, w16 + oW2r, s2bl, nullptr, nullptr, nullptr, nullptr, bufZ);

    // node-side projection of predictor W1 (Za into bufX, Zb into bufH)
    proj16_kernel<<<(Nn + 63) / 64, 256, 0, stream>>>(bufZ, w16 + oW1a, w16 + oW1b, bufX, bufH);

    // fused per-edge predictor
    edge_kernel<<<Pp / EPB, 256, 0, stream>>>(pe, ef, bufX, bufH, w16, bnA, pb3, out);
}

// Round 5
// 1091.967 us; speedup vs baseline: 2.9352x; 1.0388x over previous
//
#include <hip/hip_runtime.h>

#define Nn 100000
#define Ee 1600000
#define Pp 1000000
#define EPSf 1e-5f

typedef _Float16 f16x8 __attribute__((ext_vector_type(8)));
typedef _Float16 f16x4 __attribute__((ext_vector_type(4)));
typedef _Float16 f16x2 __attribute__((ext_vector_type(2)));
typedef float f32x4 __attribute__((ext_vector_type(4)));

__device__ __forceinline__ float4 ld4(const float* p) { return *(const float4*)p; }

// f16 weight arena offsets (elements)
#define oW1l 0        // 128x128
#define oW1r 16384    // 128x128
#define oW2l 32768    // 64x128
#define oW2r 40960    // 64x128
#define oW1a 49152    // 128x64   (pW1 cols 0..63)
#define oW1b 57344    // 128x64   (pW1 cols 64..127)
#define oW1c 65536    // 128x32   (pW1 cols 128..159)
#define oWe1 69632    // 64x32
#define oWe2 71680    // 32x64
#define oWp2 73728    // 64x128
#define W16_TOTAL 81920

// BN-const arena layout (floats)
#define BN_TOTAL 608

// ---------------- prep: f32 -> f16 weights/x + BN const folding ----------------
__global__ __launch_bounds__(256) void prep_kernel(
    const float* __restrict__ x,
    const float* __restrict__ s1Wl, const float* __restrict__ s1Wr,
    const float* __restrict__ s2Wl, const float* __restrict__ s2Wr,
    const float* __restrict__ pW1,  const float* __restrict__ eW1,
    const float* __restrict__ eW2,  const float* __restrict__ pW2,
    const float* __restrict__ eb1,
    const float* __restrict__ ebng, const float* __restrict__ ebnb,
    const float* __restrict__ ebnm, const float* __restrict__ ebnv,
    const float* __restrict__ eb2,
    const float* __restrict__ pb1,
    const float* __restrict__ p1g, const float* __restrict__ p1b,
    const float* __restrict__ p1m, const float* __restrict__ p1v,
    const float* __restrict__ pb2,
    const float* __restrict__ p2g, const float* __restrict__ p2b,
    const float* __restrict__ p2m, const float* __restrict__ p2v,
    const float* __restrict__ pW3,
    _Float16* __restrict__ w16, float* __restrict__ bnA,
    _Float16* __restrict__ x16) {
    int tid = blockIdx.x * 256 + threadIdx.x;
    if (tid < W16_TOTAL) {
        float v;
        if (tid < 16384)      v = s1Wl[tid];
        else if (tid < 32768) v = s1Wr[tid - 16384];
        else if (tid < 40960) v = s2Wl[tid - 32768];
        else if (tid < 49152) v = s2Wr[tid - 40960];
        else if (tid < 57344) { int l = tid - 49152; v = pW1[(l >> 6) * 160 + (l & 63)]; }
        else if (tid < 65536) { int l = tid - 57344; v = pW1[(l >> 6) * 160 + 64 + (l & 63)]; }
        else if (tid < 69632) { int l = tid - 65536; v = pW1[(l >> 5) * 160 + 128 + (l & 31)]; }
        else if (tid < 71680) v = eW1[tid - 69632];
        else if (tid < 73728) v = eW2[tid - 71680];
        else                  v = pW2[tid - 73728];
        w16[tid] = (_Float16)v;
    } else if (tid < W16_TOTAL + BN_TOTAL) {
        int b = tid - W16_TOTAL;
        float v;
        if (b < 64)       v = ebng[b] * rsqrtf(ebnv[b] + EPSf);
        else if (b < 128) { int c = b - 64;  float s = ebng[c] * rsqrtf(ebnv[c] + EPSf);
                            v = (eb1[c] - ebnm[c]) * s + ebnb[c]; }
        else if (b < 256) { int c = b - 128; v = p1g[c] * rsqrtf(p1v[c] + EPSf); }
        else if (b < 384) { int c = b - 256; float s = p1g[c] * rsqrtf(p1v[c] + EPSf);
                            v = (pb1[c] - p1m[c]) * s + p1b[c]; }
        else if (b < 448) { int c = b - 384; v = p2g[c] * rsqrtf(p2v[c] + EPSf); }
        else if (b < 512) { int c = b - 448; float s = p2g[c] * rsqrtf(p2v[c] + EPSf);
                            v = (pb2[c] - p2m[c]) * s + p2b[c]; }
        else if (b < 544) v = eb2[b - 512];
        else              v = pW3[b - 544];
        bnA[b] = v;
    }
    int stride = gridDim.x * 256;
    const int NV = Nn * 128 / 4;
    for (int i = tid; i < NV; i += stride) {
        float4 v = ((const float4*)x)[i];
        f16x4 h = {(_Float16)v.x, (_Float16)v.y, (_Float16)v.z, (_Float16)v.w};
        ((f16x4*)x16)[i] = h;
    }
}

// ---------------- CSR build ----------------
__global__ __launch_bounds__(256) void hist_kernel(const int* __restrict__ dst,
                                                   unsigned* __restrict__ deg) {
    int i = blockIdx.x * 256 + threadIdx.x;
    if (i < Ee) atomicAdd(&deg[dst[i]], 1u);
}

// 3-phase coalesced parallel scan
__global__ __launch_bounds__(1024) void scanA_kernel(const unsigned* __restrict__ deg,
                                                     unsigned* __restrict__ escan,
                                                     unsigned* __restrict__ bsum) {
    __shared__ unsigned s[1024];
    int t = threadIdx.x;
    int gid = blockIdx.x * 1024 + t;
    unsigned v = (gid < Nn) ? deg[gid] : 0u;
    s[t] = v;
    __syncthreads();
    for (int off = 1; off < 1024; off <<= 1) {
        unsigned u = (t >= off) ? s[t - off] : 0u;
        __syncthreads();
        s[t] += u;
        __syncthreads();
    }
    if (gid < Nn) escan[gid] = s[t] - v;
    if (t == 1023) bsum[blockIdx.x] = s[1023];
}

__global__ __launch_bounds__(128) void scanB_kernel(const unsigned* __restrict__ bsum,
                                                    unsigned* __restrict__ boff,
                                                    int nblk) {
    __shared__ unsigned s[128];
    int t = threadIdx.x;
    unsigned v = (t < nblk) ? bsum[t] : 0u;
    s[t] = v;
    __syncthreads();
    for (int off = 1; off < 128; off <<= 1) {
        unsigned u = (t >= off) ? s[t - off] : 0u;
        __syncthreads();
        s[t] += u;
        __syncthreads();
    }
    if (t < nblk) boff[t] = s[t] - v;
}

__global__ __launch_bounds__(1024) void scanC_kernel(const unsigned* __restrict__ escan,
                                                     const unsigned* __restrict__ boff,
                                                     int* __restrict__ rowptr,
                                                     int* __restrict__ cursor) {
    int t = threadIdx.x;
    int gid = blockIdx.x * 1024 + t;
    if (gid < Nn) {
        int v = (int)(escan[gid] + boff[blockIdx.x]);
        rowptr[gid] = v;
        cursor[gid] = v;
    }
    if (gid == 0) rowptr[Nn] = Ee;
}

__global__ __launch_bounds__(256) void scatter_kernel(const int* __restrict__ src,
                                                      const int* __restrict__ dst,
                                                      int* __restrict__ cursor,
                                                      int* __restrict__ elist) {
    int i = blockIdx.x * 256 + threadIdx.x;
    if (i < Ee) {
        int p = atomicAdd(&cursor[dst[i]], 1);
        elist[p] = src[i];
    }
}

// ---------------- f16 mean aggregation: wave/node, multi-row per load-inst ----
template<int W>
__global__ __launch_bounds__(256, 8) void aggregate16_kernel(
    const _Float16* __restrict__ feat,
    const int* __restrict__ rowptr,
    const int* __restrict__ elist,
    _Float16* __restrict__ outp) {
    int node = (blockIdx.x * 256 + threadIdx.x) >> 6;
    int lane = threadIdx.x & 63;
    if (node >= Nn) return;
    constexpr int SEGS = W / 8;        // 16B segments per row
    constexpr int RPI  = 64 / SEGS;    // rows per wave-instruction
    const int r = lane / SEGS, c = lane % SEGS;
    int beg = rowptr[node], end = rowptr[node + 1];
    int n = end - beg;
    float acc[8];
#pragma unroll
    for (int k = 0; k < 8; ++k) acc[k] = 0.f;
    for (int c0 = 0; c0 < n; c0 += 64) {
        int m = min(64, n - c0);
        int se = (lane < m) ? elist[beg + c0 + lane] : 0;
        int iters = (m + RPI - 1) / RPI;
#pragma unroll 2
        for (int i = 0; i < iters; ++i) {
            int j = i * RPI + r;
            int s = __shfl(se, j);
            if (j < m) {
                f16x8 v = *(const f16x8*)(feat + (size_t)s * W + c * 8);
#pragma unroll
                for (int k = 0; k < 8; ++k) acc[k] += (float)v[k];
            }
        }
    }
#pragma unroll
    for (int k = 0; k < 8; ++k) {
#pragma unroll
        for (int off = SEGS; off < 64; off <<= 1)
            acc[k] += __shfl_xor(acc[k], off);
    }
    if (r == 0) {
        float inv = 1.0f / fmaxf((float)n, 1.0f);
        f16x8 o;
#pragma unroll
        for (int k = 0; k < 8; ++k) o[k] = (_Float16)(acc[k] * inv);
        *(f16x8*)(outp + (size_t)node * W + c * 8) = o;
    }
}

// ---------------- dense SAGE layer 1 via MFMA (register-only) ----------------
__global__ __launch_bounds__(256) void dense1_kernel(
    const _Float16* __restrict__ A1, const _Float16* __restrict__ A2,
    const _Float16* __restrict__ W1, const _Float16* __restrict__ W2,
    const float* __restrict__ lb,
    const float* __restrict__ bng, const float* __restrict__ bnb,
    const float* __restrict__ bnm, const float* __restrict__ bnv,
    _Float16* __restrict__ out) {
    const int t = threadIdx.x;
    const int w = t >> 6, lane = t & 63;
    const int lrow = lane & 15, lq = lane >> 4;
    const int row0 = blockIdx.x * 64 + w * 16;
    const int ld = min(row0 + lrow, Nn - 1);

    f16x8 a1[4], a2[4];
#pragma unroll
    for (int i = 0; i < 4; ++i) {
        a1[i] = *(const f16x8*)(A1 + (size_t)ld * 128 + i * 32 + lq * 8);
        a2[i] = *(const f16x8*)(A2 + (size_t)ld * 128 + i * 32 + lq * 8);
    }
#pragma unroll
    for (int nt = 0; nt < 8; ++nt) {
        const _Float16* w1r = W1 + (size_t)(nt * 16 + lrow) * 128;
        const _Float16* w2r = W2 + (size_t)(nt * 16 + lrow) * 128;
        f32x4 c = {0.f, 0.f, 0.f, 0.f};
#pragma unroll
        for (int i = 0; i < 4; ++i) {
            c = __builtin_amdgcn_mfma_f32_16x16x32_f16(a1[i], *(const f16x8*)(w1r + i * 32 + lq * 8), c, 0, 0, 0);
            c = __builtin_amdgcn_mfma_f32_16x16x32_f16(a2[i], *(const f16x8*)(w2r + i * 32 + lq * 8), c, 0, 0, 0);
        }
        int cc = nt * 16 + lrow;
        float s = bng[cc] * rsqrtf(bnv[cc] + EPSf);
        float h = (lb[cc] - bnm[cc]) * s + bnb[cc];
#pragma unroll
        for (int r = 0; r < 4; ++r) {
            int gr = row0 + lq * 4 + r;
            if (gr < Nn)
                out[(size_t)gr * 128 + cc] = (_Float16)fmaxf(c[r] * s + h, 0.f);
        }
    }
}

// ---------------- y = h @ W2l^T  (K=128, NOUT=64, raw) ----------------
__global__ __launch_bounds__(256) void gemmY_kernel(
    const _Float16* __restrict__ A, const _Float16* __restrict__ W,
    _Float16* __restrict__ out) {
    const int t = threadIdx.x;
    const int w = t >> 6, lane = t & 63;
    const int lrow = lane & 15, lq = lane >> 4;
    const int row0 = blockIdx.x * 64 + w * 16;
    const int ld = min(row0 + lrow, Nn - 1);
    f16x8 a[4];
#pragma unroll
    for (int i = 0; i < 4; ++i)
        a[i] = *(const f16x8*)(A + (size_t)ld * 128 + i * 32 + lq * 8);
#pragma unroll
    for (int nt = 0; nt < 4; ++nt) {
        const _Float16* wr = W + (size_t)(nt * 16 + lrow) * 128;
        f32x4 c = {0.f, 0.f, 0.f, 0.f};
#pragma unroll
        for (int i = 0; i < 4; ++i)
            c = __builtin_amdgcn_mfma_f32_16x16x32_f16(a[i], *(const f16x8*)(wr + i * 32 + lq * 8), c, 0, 0, 0);
        int cc = nt * 16 + lrow;
#pragma unroll
        for (int r = 0; r < 4; ++r) {
            int gr = row0 + lq * 4 + r;
            if (gr < Nn) out[(size_t)gr * 64 + cc] = (_Float16)c[r];
        }
    }
}

// ---------------- z = aggY + h @ W2r^T + lb  (K=128, NOUT=64) ----------------
__global__ __launch_bounds__(256) void dense2b_kernel(
    const _Float16* __restrict__ aggY, const _Float16* __restrict__ A2,
    const _Float16* __restrict__ W2, const float* __restrict__ lb,
    _Float16* __restrict__ out) {
    const int t = threadIdx.x;
    const int w = t >> 6, lane = t & 63;
    const int lrow = lane & 15, lq = lane >> 4;
    const int row0 = blockIdx.x * 64 + w * 16;
    const int ld = min(row0 + lrow, Nn - 1);
    f16x8 a[4];
#pragma unroll
    for (int i = 0; i < 4; ++i)
        a[i] = *(const f16x8*)(A2 + (size_t)ld * 128 + i * 32 + lq * 8);
#pragma unroll
    for (int nt = 0; nt < 4; ++nt) {
        const _Float16* wr = W2 + (size_t)(nt * 16 + lrow) * 128;
        f32x4 c = {0.f, 0.f, 0.f, 0.f};
#pragma unroll
        for (int i = 0; i < 4; ++i)
            c = __builtin_amdgcn_mfma_f32_16x16x32_f16(a[i], *(const f16x8*)(wr + i * 32 + lq * 8), c, 0, 0, 0);
        int cc = nt * 16 + lrow;
        float b = lb[cc];
#pragma unroll
        for (int r = 0; r < 4; ++r) {
            int gr = row0 + lq * 4 + r;
            if (gr < Nn) {
                float g = (float)aggY[(size_t)gr * 64 + cc];
                out[(size_t)gr * 64 + cc] = (_Float16)(c[r] + g + b);
            }
        }
    }
}

// ---------------- fused per-edge predictor: gather z, project in-kernel ----
#define EPB 64
#define oE1  0       // e1 f16 [64][72]  9216 B  (aliased by U2)
#define oE2  9216    // e2 f16 [64][40]  5120 B
#define oZU  14336   // f16 [64][144]: za cols 0..63, zb 64..127 -> u1 cols 0..127
#define SMEM_BYTES 32768

__global__ __launch_bounds__(256, 5) void edge_kernel(
    const int* __restrict__ pe,
    const float* __restrict__ ef,
    const _Float16* __restrict__ z,      // [N,64]
    const _Float16* __restrict__ w16,
    const float* __restrict__ bnA,
    const float* __restrict__ pb3,
    float* __restrict__ out) {
    __shared__ __align__(16) unsigned char smem[SMEM_BYTES];
    _Float16* E1 = (_Float16*)(smem + oE1);
    _Float16* E2 = (_Float16*)(smem + oE2);
    _Float16* ZU = (_Float16*)(smem + oZU);
    _Float16* U2 = (_Float16*)(smem + oE1);   // alias: E1 dead after P3

    const _Float16* We1 = w16 + oWe1;
    const _Float16* We2 = w16 + oWe2;
    const _Float16* W1a = w16 + oW1a;
    const _Float16* W1b = w16 + oW1b;
    const _Float16* W1c = w16 + oW1c;
    const _Float16* Wp2 = w16 + oWp2;
    const float* bn1s = bnA;        const float* bn1h = bnA + 64;
    const float* bn2s = bnA + 128;  const float* bn2h = bnA + 256;
    const float* bn3s = bnA + 384;  const float* bn3h = bnA + 448;
    const float* eb2g = bnA + 512;  const float* wp3g = bnA + 544;

    const int t = threadIdx.x;
    const int base = blockIdx.x * EPB;
    const int lane = t & 63;
    const int w = t >> 6;
    const int m0 = w * 16;
    const int lrow = lane & 15;
    const int lq = lane >> 4;
    const int er = lane >> 3;       // gather: 8 rows per instruction
    const int seg = lane & 7;       // 16B segment within 128B row

    // ---- gather z rows for both endpoints (4 random-row load insts) ----
    f16x8 ga[2], gb[2];
#pragma unroll
    for (int i = 0; i < 2; ++i) {
        int e = m0 + i * 8 + er;
        int ai = pe[base + e];
        int bi = pe[Pp + base + e];
        ga[i] = *(const f16x8*)(z + (size_t)ai * 64 + seg * 8);
        gb[i] = *(const f16x8*)(z + (size_t)bi * 64 + seg * 8);
    }

    // ---- P2: e1 = relu(bn(ef @ eW1^T)), [16x32]@[32x64] ----
    {
        const float* src = ef + (size_t)(base + m0 + lrow) * 32 + lq * 8;
        float4 v0 = ld4(src), v1 = ld4(src + 4);
        f16x8 a = {(_Float16)v0.x, (_Float16)v0.y, (_Float16)v0.z, (_Float16)v0.w,
                   (_Float16)v1.x, (_Float16)v1.y, (_Float16)v1.z, (_Float16)v1.w};
#pragma unroll
        for (int nt = 0; nt < 4; ++nt) {
            f16x8 b = *(const f16x8*)(We1 + (nt * 16 + lrow) * 32 + lq * 8);
            f32x4 c = {0.f, 0.f, 0.f, 0.f};
            c = __builtin_amdgcn_mfma_f32_16x16x32_f16(a, b, c, 0, 0, 0);
            int cc = nt * 16 + lrow;
            float s = bn1s[cc], h = bn1h[cc];
#pragma unroll
            for (int r = 0; r < 4; ++r) {
                int rr = m0 + lq * 4 + r;
                E1[rr * 72 + cc] = (_Float16)fmaxf(c[r] * s + h, 0.f);
            }
        }
    }
    // ---- park gathered z rows in LDS (za: cols 0..63, zb: 64..127) ----
#pragma unroll
    for (int i = 0; i < 2; ++i) {
        int e = m0 + i * 8 + er;
        *(f16x8*)(ZU + e * 144 + seg * 8) = ga[i];
        *(f16x8*)(ZU + e * 144 + 64 + seg * 8) = gb[i];
    }
    // ---- P3: e2 = e1 @ eW2^T + eb2, [16x64]@[64x32] ----
    {
        f16x8 a0 = *(const f16x8*)(E1 + (m0 + lrow) * 72 + lq * 8);
        f16x8 a1 = *(const f16x8*)(E1 + (m0 + lrow) * 72 + 32 + lq * 8);
#pragma unroll
        for (int nt = 0; nt < 2; ++nt) {
            f16x8 b0 = *(const f16x8*)(We2 + (nt * 16 + lrow) * 64 + lq * 8);
            f16x8 b1 = *(const f16x8*)(We2 + (nt * 16 + lrow) * 64 + 32 + lq * 8);
            f32x4 c = {0.f, 0.f, 0.f, 0.f};
            c = __builtin_amdgcn_mfma_f32_16x16x32_f16(a0, b0, c, 0, 0, 0);
            c = __builtin_amdgcn_mfma_f32_16x16x32_f16(a1, b1, c, 0, 0, 0);
            int cc = nt * 16 + lrow;
            float bias = eb2g[cc];
#pragma unroll
            for (int r = 0; r < 4; ++r) {
                int rr = m0 + lq * 4 + r;
                E2[rr * 40 + cc] = (_Float16)(c[r] + bias);
            }
        }
    }
    // ---- P4: u1 = relu(bn1(za@W1a^T + zb@W1b^T + e2@W1c^T)), NOUT=128 ----
    {
        f16x8 za0 = *(const f16x8*)(ZU + (m0 + lrow) * 144 + lq * 8);
        f16x8 za1 = *(const f16x8*)(ZU + (m0 + lrow) * 144 + 32 + lq * 8);
        f16x8 zb0 = *(const f16x8*)(ZU + (m0 + lrow) * 144 + 64 + lq * 8);
        f16x8 zb1 = *(const f16x8*)(ZU + (m0 + lrow) * 144 + 96 + lq * 8);
        f16x8 ae  = *(const f16x8*)(E2 + (m0 + lrow) * 40 + lq * 8);
#pragma unroll
        for (int nt = 0; nt < 8; ++nt) {
            const _Float16* wa = W1a + (nt * 16 + lrow) * 64;
            const _Float16* wb = W1b + (nt * 16 + lrow) * 64;
            const _Float16* wc = W1c + (nt * 16 + lrow) * 32;
            f32x4 c = {0.f, 0.f, 0.f, 0.f};
            c = __builtin_amdgcn_mfma_f32_16x16x32_f16(za0, *(const f16x8*)(wa + lq * 8),      c, 0, 0, 0);
            c = __builtin_amdgcn_mfma_f32_16x16x32_f16(za1, *(const f16x8*)(wa + 32 + lq * 8), c, 0, 0, 0);
            c = __builtin_amdgcn_mfma_f32_16x16x32_f16(zb0, *(const f16x8*)(wb + lq * 8),      c, 0, 0, 0);
            c = __builtin_amdgcn_mfma_f32_16x16x32_f16(zb1, *(const f16x8*)(wb + 32 + lq * 8), c, 0, 0, 0);
            c = __builtin_amdgcn_mfma_f32_16x16x32_f16(ae,  *(const f16x8*)(wc + lq * 8),      c, 0, 0, 0);
            int cc = nt * 16 + lrow;
            float s = bn2s[cc], h = bn2h[cc];
#pragma unroll
            for (int r = 0; r < 4; ++r) {
                int rr = m0 + lq * 4 + r;
                ZU[rr * 144 + cc] = (_Float16)fmaxf(c[r] * s + h, 0.f);
            }
        }
    }
    // ---- P6: u2 = relu(bn2(u1 @ pW2^T)), [16x128]@[128x64] ----
    {
        f16x8 a0 = *(const f16x8*)(ZU + (m0 + lrow) * 144 + 0  + lq * 8);
        f16x8 a1 = *(const f16x8*)(ZU + (m0 + lrow) * 144 + 32 + lq * 8);
        f16x8 a2 = *(const f16x8*)(ZU + (m0 + lrow) * 144 + 64 + lq * 8);
        f16x8 a3 = *(const f16x8*)(ZU + (m0 + lrow) * 144 + 96 + lq * 8);
#pragma unroll
        for (int nt = 0; nt < 4; ++nt) {
            const _Float16* wr = Wp2 + (nt * 16 + lrow) * 128 + lq * 8;
            f32x4 c = {0.f, 0.f, 0.f, 0.f};
            c = __builtin_amdgcn_mfma_f32_16x16x32_f16(a0, *(const f16x8*)(wr + 0),  c, 0, 0, 0);
            c = __builtin_amdgcn_mfma_f32_16x16x32_f16(a1, *(const f16x8*)(wr + 32), c, 0, 0, 0);
            c = __builtin_amdgcn_mfma_f32_16x16x32_f16(a2, *(const f16x8*)(wr + 64), c, 0, 0, 0);
            c = __builtin_amdgcn_mfma_f32_16x16x32_f16(a3, *(const f16x8*)(wr + 96), c, 0, 0, 0);
            int cc = nt * 16 + lrow;
            float s = bn3s[cc], h = bn3h[cc];
#pragma unroll
            for (int r = 0; r < 4; ++r) {
                int rr = m0 + lq * 4 + r;
                U2[rr * 72 + cc] = (_Float16)fmaxf(c[r] * s + h, 0.f);
            }
        }
    }
    // ---- P7: out = u2 @ pW3 + pb3 (4 lanes per edge) ----
    {
        int e = m0 + (lane >> 2);
        int c0 = (lane & 3) * 16;
        f16x8 u0 = *(const f16x8*)(U2 + e * 72 + c0);
        f16x8 u1 = *(const f16x8*)(U2 + e * 72 + c0 + 8);
        float acc = 0.f;
#pragma unroll
        for (int j = 0; j < 8; ++j) acc += (float)u0[j] * wp3g[c0 + j];
#pragma unroll
        for (int j = 0; j < 8; ++j) acc += (float)u1[j] * wp3g[c0 + 8 + j];
        acc += __shfl_xor(acc, 1);
        acc += __shfl_xor(acc, 2);
        if ((lane & 3) == 0) out[base + e] = acc + pb3[0];
    }
}

// ---------------- launch ----------------
extern "C" void kernel_launch(void* const* d_in, const int* in_sizes, int n_in,
                              void* d_out, int out_size, void* d_ws, size_t ws_size,
                              hipStream_t stream) {
    const float* x    = (const float*)d_in[0];
    const int*   eidx = (const int*)d_in[1];
    const int*   pe   = (const int*)d_in[2];
    const float* ef   = (const float*)d_in[3];
    const float* s1Wl = (const float*)d_in[4];
    const float* s1bl = (const float*)d_in[5];
    const float* s1Wr = (const float*)d_in[6];
    const float* bn1g = (const float*)d_in[7];
    const float* bn1b = (const float*)d_in[8];
    const float* bn1m = (const float*)d_in[9];
    const float* bn1v = (const float*)d_in[10];
    const float* s2Wl = (const float*)d_in[11];
    const float* s2bl = (const float*)d_in[12];
    const float* s2Wr = (const float*)d_in[13];
    const float* eW1  = (const float*)d_in[14];
    const float* eb1  = (const float*)d_in[15];
    const float* ebng = (const float*)d_in[16];
    const float* ebnb = (const float*)d_in[17];
    const float* ebnm = (const float*)d_in[18];
    const float* ebnv = (const float*)d_in[19];
    const float* eW2  = (const float*)d_in[20];
    const float* eb2  = (const float*)d_in[21];
    const float* pW1  = (const float*)d_in[22];
    const float* pb1  = (const float*)d_in[23];
    const float* p1g  = (const float*)d_in[24];
    const float* p1b  = (const float*)d_in[25];
    const float* p1m  = (const float*)d_in[26];
    const float* p1v  = (const float*)d_in[27];
    const float* pW2  = (const float*)d_in[28];
    const float* pb2  = (const float*)d_in[29];
    const float* p2g  = (const float*)d_in[30];
    const float* p2b  = (const float*)d_in[31];
    const float* p2m  = (const float*)d_in[32];
    const float* p2v  = (const float*)d_in[33];
    const float* pW3  = (const float*)d_in[34];
    const float* pb3  = (const float*)d_in[35];
    float* out = (float*)d_out;

    char* wk = (char*)d_ws;
    auto carve = [&](size_t bytes) {
        char* p = wk;
        wk += (bytes + 255) & ~(size_t)255;
        return p;
    };
    unsigned*  deg    = (unsigned*)carve((size_t)Nn * 4);
    int*       rowptr = (int*)carve((size_t)(Nn + 1) * 4);
    int*       cursor = (int*)carve((size_t)Nn * 4);
    int*       elist  = (int*)carve((size_t)Ee * 4);
    unsigned*  escan  = (unsigned*)carve((size_t)Nn * 4);
    unsigned*  bsum   = (unsigned*)carve(128 * 4);
    unsigned*  boff   = (unsigned*)carve(128 * 4);
    _Float16*  w16    = (_Float16*)carve((size_t)W16_TOTAL * 2);
    float*     bnA    = (float*)carve((size_t)BN_TOTAL * 4);
    _Float16*  bufX   = (_Float16*)carve((size_t)Nn * 128 * 2);  // x16; later bufY+bufZ
    _Float16*  bufA   = (_Float16*)carve((size_t)Nn * 128 * 2);  // agg1 out; later aggY
    _Float16*  bufH   = (_Float16*)carve((size_t)Nn * 128 * 2);  // h
    _Float16*  bufY   = bufX;                                    // y (64-w) in x16's first half
    _Float16*  bufZ   = bufX + (size_t)Nn * 64;                  // z (64-w) in x16's second half
    _Float16*  bufAy  = bufA;                                    // aggregated y

    const int* e_src = eidx;
    const int* e_dst = eidx + Ee;
    const int SBLK = (Nn + 1023) / 1024;   // 98

    hipMemsetAsync(deg, 0, (size_t)Nn * 4, stream);
    prep_kernel<<<800, 256, 0, stream>>>(x, s1Wl, s1Wr, s2Wl, s2Wr, pW1, eW1, eW2, pW2,
                                         eb1, ebng, ebnb, ebnm, ebnv, eb2,
                                         pb1, p1g, p1b, p1m, p1v,
                                         pb2, p2g, p2b, p2m, p2v, pW3,
                                         w16, bnA, bufX);
    hist_kernel<<<(Ee + 255) / 256, 256, 0, stream>>>(e_dst, deg);
    scanA_kernel<<<SBLK, 1024, 0, stream>>>(deg, escan, bsum);
    scanB_kernel<<<1, 128, 0, stream>>>(bsum, boff, SBLK);
    scanC_kernel<<<SBLK, 1024, 0, stream>>>(escan, boff, rowptr, cursor);
    scatter_kernel<<<(Ee + 255) / 256, 256, 0, stream>>>(e_src, e_dst, cursor, elist);

    // SAGE layer 1: h = relu(bn(agg(x)@W1l^T + x@W1r^T + b))
    aggregate16_kernel<128><<<Nn / 4, 256, 0, stream>>>(bufX, rowptr, elist, bufA);
    dense1_kernel<<<(Nn + 63) / 64, 256, 0, stream>>>(
        bufA, bufX, w16 + oW1l, w16 + oW1r, s1bl, bn1g, bn1b, bn1m, bn1v, bufH);

    // SAGE layer 2 (linear commutes with mean): y = h@W2l^T; z = agg(y) + h@W2r^T + b
    gemmY_kernel<<<(Nn + 63) / 64, 256, 0, stream>>>(bufH, w16 + oW2l, bufY);
    aggregate16_kernel<64><<<Nn / 4, 256, 0, stream>>>(bufY, rowptr, elist, bufAy);
    dense2b_kernel<<<(Nn + 63) / 64, 256, 0, stream>>>(
        bufAy, bufH, w16 + oW2r, s2bl, bufZ);

    // fused per-edge predictor (gathers z directly, projects in-kernel)
    edge_kernel<<<Pp / EPB, 256, 0, stream>>>(pe, ef, bufZ, w16, bnA, pb3, out);
}

// Round 6
// 783.220 us; speedup vs baseline: 4.0923x; 1.3942x over previous
//
#include <hip/hip_runtime.h>

#define Nn 100000
#define Ee 1600000
#define Pp 1000000
#define EPSf 1e-5f

typedef _Float16 f16x8 __attribute__((ext_vector_type(8)));
typedef _Float16 f16x4 __attribute__((ext_vector_type(4)));
typedef _Float16 f16x2 __attribute__((ext_vector_type(2)));
typedef float f32x4 __attribute__((ext_vector_type(4)));

__device__ __forceinline__ float4 ld4(const float* p) { return *(const float4*)p; }

// f16 weight arena offsets (elements)
#define oW1l 0        // 128x128
#define oW1r 16384    // 128x128
#define oW2l 32768    // 64x128
#define oW2r 40960    // 64x128
#define oW1a 49152    // 128x64   (pW1 cols 0..63)
#define oW1b 57344    // 128x64   (pW1 cols 64..127)
#define oW1c 65536    // 128x32   (pW1 cols 128..159)
#define oWe1 69632    // 64x32
#define oWe2 71680    // 32x64
#define oWp2 73728    // 64x128
#define W16_TOTAL 81920

#define BN_TOTAL 608

// ---------------- prep: f32 -> f16 weights/x + BN const folding ----------------
__global__ __launch_bounds__(256) void prep_kernel(
    const float* __restrict__ x,
    const float* __restrict__ s1Wl, const float* __restrict__ s1Wr,
    const float* __restrict__ s2Wl, const float* __restrict__ s2Wr,
    const float* __restrict__ pW1,  const float* __restrict__ eW1,
    const float* __restrict__ eW2,  const float* __restrict__ pW2,
    const float* __restrict__ eb1,
    const float* __restrict__ ebng, const float* __restrict__ ebnb,
    const float* __restrict__ ebnm, const float* __restrict__ ebnv,
    const float* __restrict__ eb2,
    const float* __restrict__ pb1,
    const float* __restrict__ p1g, const float* __restrict__ p1b,
    const float* __restrict__ p1m, const float* __restrict__ p1v,
    const float* __restrict__ pb2,
    const float* __restrict__ p2g, const float* __restrict__ p2b,
    const float* __restrict__ p2m, const float* __restrict__ p2v,
    const float* __restrict__ pW3,
    _Float16* __restrict__ w16, float* __restrict__ bnA,
    _Float16* __restrict__ x16) {
    int tid = blockIdx.x * 256 + threadIdx.x;
    if (tid < W16_TOTAL) {
        float v;
        if (tid < 16384)      v = s1Wl[tid];
        else if (tid < 32768) v = s1Wr[tid - 16384];
        else if (tid < 40960) v = s2Wl[tid - 32768];
        else if (tid < 49152) v = s2Wr[tid - 40960];
        else if (tid < 57344) { int l = tid - 49152; v = pW1[(l >> 6) * 160 + (l & 63)]; }
        else if (tid < 65536) { int l = tid - 57344; v = pW1[(l >> 6) * 160 + 64 + (l & 63)]; }
        else if (tid < 69632) { int l = tid - 65536; v = pW1[(l >> 5) * 160 + 128 + (l & 31)]; }
        else if (tid < 71680) v = eW1[tid - 69632];
        else if (tid < 73728) v = eW2[tid - 71680];
        else                  v = pW2[tid - 73728];
        w16[tid] = (_Float16)v;
    } else if (tid < W16_TOTAL + BN_TOTAL) {
        int b = tid - W16_TOTAL;
        float v;
        if (b < 64)       v = ebng[b] * rsqrtf(ebnv[b] + EPSf);
        else if (b < 128) { int c = b - 64;  float s = ebng[c] * rsqrtf(ebnv[c] + EPSf);
                            v = (eb1[c] - ebnm[c]) * s + ebnb[c]; }
        else if (b < 256) { int c = b - 128; v = p1g[c] * rsqrtf(p1v[c] + EPSf); }
        else if (b < 384) { int c = b - 256; float s = p1g[c] * rsqrtf(p1v[c] + EPSf);
                            v = (pb1[c] - p1m[c]) * s + p1b[c]; }
        else if (b < 448) { int c = b - 384; v = p2g[c] * rsqrtf(p2v[c] + EPSf); }
        else if (b < 512) { int c = b - 448; float s = p2g[c] * rsqrtf(p2v[c] + EPSf);
                            v = (pb2[c] - p2m[c]) * s + p2b[c]; }
        else if (b < 544) v = eb2[b - 512];
        else              v = pW3[b - 544];
        bnA[b] = v;
    }
    int stride = gridDim.x * 256;
    const int NV = Nn * 128 / 4;
    for (int i = tid; i < NV; i += stride) {
        float4 v = ((const float4*)x)[i];
        f16x4 h = {(_Float16)v.x, (_Float16)v.y, (_Float16)v.z, (_Float16)v.w};
        ((f16x4*)x16)[i] = h;
    }
}

// ---------------- CSR build ----------------
__global__ __launch_bounds__(256) void hist_kernel(const int* __restrict__ dst,
                                                   unsigned* __restrict__ deg) {
    int i = blockIdx.x * 256 + threadIdx.x;
    if (i < Ee) atomicAdd(&deg[dst[i]], 1u);
}

__global__ __launch_bounds__(1024) void scanA_kernel(const unsigned* __restrict__ deg,
                                                     unsigned* __restrict__ escan,
                                                     unsigned* __restrict__ bsum) {
    __shared__ unsigned s[1024];
    int t = threadIdx.x;
    int gid = blockIdx.x * 1024 + t;
    unsigned v = (gid < Nn) ? deg[gid] : 0u;
    s[t] = v;
    __syncthreads();
    for (int off = 1; off < 1024; off <<= 1) {
        unsigned u = (t >= off) ? s[t - off] : 0u;
        __syncthreads();
        s[t] += u;
        __syncthreads();
    }
    if (gid < Nn) escan[gid] = s[t] - v;
    if (t == 1023) bsum[blockIdx.x] = s[1023];
}

__global__ __launch_bounds__(128) void scanB_kernel(const unsigned* __restrict__ bsum,
                                                    unsigned* __restrict__ boff,
                                                    int nblk) {
    __shared__ unsigned s[128];
    int t = threadIdx.x;
    unsigned v = (t < nblk) ? bsum[t] : 0u;
    s[t] = v;
    __syncthreads();
    for (int off = 1; off < 128; off <<= 1) {
        unsigned u = (t >= off) ? s[t - off] : 0u;
        __syncthreads();
        s[t] += u;
        __syncthreads();
    }
    if (t < nblk) boff[t] = s[t] - v;
}

__global__ __launch_bounds__(1024) void scanC_kernel(const unsigned* __restrict__ escan,
                                                     const unsigned* __restrict__ boff,
                                                     int* __restrict__ rowptr,
                                                     int* __restrict__ cursor) {
    int t = threadIdx.x;
    int gid = blockIdx.x * 1024 + t;
    if (gid < Nn) {
        int v = (int)(escan[gid] + boff[blockIdx.x]);
        rowptr[gid] = v;
        cursor[gid] = v;
    }
    if (gid == 0) rowptr[Nn] = Ee;
}

__global__ __launch_bounds__(256) void scatter_kernel(const int* __restrict__ src,
                                                      const int* __restrict__ dst,
                                                      int* __restrict__ cursor,
                                                      int* __restrict__ elist) {
    int i = blockIdx.x * 256 + threadIdx.x;
    if (i < Ee) {
        int p = atomicAdd(&cursor[dst[i]], 1);
        elist[p] = src[i];
    }
}

// ---------------- f16 mean aggregation ----------------
template<int W>
__global__ __launch_bounds__(256, 8) void aggregate16_kernel(
    const _Float16* __restrict__ feat,
    const int* __restrict__ rowptr,
    const int* __restrict__ elist,
    _Float16* __restrict__ outp) {
    int node = (blockIdx.x * 256 + threadIdx.x) >> 6;
    int lane = threadIdx.x & 63;
    if (node >= Nn) return;
    constexpr int SEGS = W / 8;
    constexpr int RPI  = 64 / SEGS;
    const int r = lane / SEGS, c = lane % SEGS;
    int beg = rowptr[node], end = rowptr[node + 1];
    int n = end - beg;
    float acc[8];
#pragma unroll
    for (int k = 0; k < 8; ++k) acc[k] = 0.f;
    for (int c0 = 0; c0 < n; c0 += 64) {
        int m = min(64, n - c0);
        int se = (lane < m) ? elist[beg + c0 + lane] : 0;
        int iters = (m + RPI - 1) / RPI;
#pragma unroll 2
        for (int i = 0; i < iters; ++i) {
            int j = i * RPI + r;
            int s = __shfl(se, j);
            if (j < m) {
                f16x8 v = *(const f16x8*)(feat + (size_t)s * W + c * 8);
#pragma unroll
                for (int k = 0; k < 8; ++k) acc[k] += (float)v[k];
            }
        }
    }
#pragma unroll
    for (int k = 0; k < 8; ++k) {
#pragma unroll
        for (int off = SEGS; off < 64; off <<= 1)
            acc[k] += __shfl_xor(acc[k], off);
    }
    if (r == 0) {
        float inv = 1.0f / fmaxf((float)n, 1.0f);
        f16x8 o;
#pragma unroll
        for (int k = 0; k < 8; ++k) o[k] = (_Float16)(acc[k] * inv);
        *(f16x8*)(outp + (size_t)node * W + c * 8) = o;
    }
}

// ---------------- dense SAGE layer 1 via MFMA ----------------
__global__ __launch_bounds__(256) void dense1_kernel(
    const _Float16* __restrict__ A1, const _Float16* __restrict__ A2,
    const _Float16* __restrict__ W1, const _Float16* __restrict__ W2,
    const float* __restrict__ lb,
    const float* __restrict__ bng, const float* __restrict__ bnb,
    const float* __restrict__ bnm, const float* __restrict__ bnv,
    _Float16* __restrict__ out) {
    const int t = threadIdx.x;
    const int w = t >> 6, lane = t & 63;
    const int lrow = lane & 15, lq = lane >> 4;
    const int row0 = blockIdx.x * 64 + w * 16;
    const int ld = min(row0 + lrow, Nn - 1);

    f16x8 a1[4], a2[4];
#pragma unroll
    for (int i = 0; i < 4; ++i) {
        a1[i] = *(const f16x8*)(A1 + (size_t)ld * 128 + i * 32 + lq * 8);
        a2[i] = *(const f16x8*)(A2 + (size_t)ld * 128 + i * 32 + lq * 8);
    }
#pragma unroll
    for (int nt = 0; nt < 8; ++nt) {
        const _Float16* w1r = W1 + (size_t)(nt * 16 + lrow) * 128;
        const _Float16* w2r = W2 + (size_t)(nt * 16 + lrow) * 128;
        f32x4 c = {0.f, 0.f, 0.f, 0.f};
#pragma unroll
        for (int i = 0; i < 4; ++i) {
            c = __builtin_amdgcn_mfma_f32_16x16x32_f16(a1[i], *(const f16x8*)(w1r + i * 32 + lq * 8), c, 0, 0, 0);
            c = __builtin_amdgcn_mfma_f32_16x16x32_f16(a2[i], *(const f16x8*)(w2r + i * 32 + lq * 8), c, 0, 0, 0);
        }
        int cc = nt * 16 + lrow;
        float s = bng[cc] * rsqrtf(bnv[cc] + EPSf);
        float h = (lb[cc] - bnm[cc]) * s + bnb[cc];
#pragma unroll
        for (int r = 0; r < 4; ++r) {
            int gr = row0 + lq * 4 + r;
            if (gr < Nn)
                out[(size_t)gr * 128 + cc] = (_Float16)fmaxf(c[r] * s + h, 0.f);
        }
    }
}

// ---------------- y = h @ W2l^T ----------------
__global__ __launch_bounds__(256) void gemmY_kernel(
    const _Float16* __restrict__ A, const _Float16* __restrict__ W,
    _Float16* __restrict__ out) {
    const int t = threadIdx.x;
    const int w = t >> 6, lane = t & 63;
    const int lrow = lane & 15, lq = lane >> 4;
    const int row0 = blockIdx.x * 64 + w * 16;
    const int ld = min(row0 + lrow, Nn - 1);
    f16x8 a[4];
#pragma unroll
    for (int i = 0; i < 4; ++i)
        a[i] = *(const f16x8*)(A + (size_t)ld * 128 + i * 32 + lq * 8);
#pragma unroll
    for (int nt = 0; nt < 4; ++nt) {
        const _Float16* wr = W + (size_t)(nt * 16 + lrow) * 128;
        f32x4 c = {0.f, 0.f, 0.f, 0.f};
#pragma unroll
        for (int i = 0; i < 4; ++i)
            c = __builtin_amdgcn_mfma_f32_16x16x32_f16(a[i], *(const f16x8*)(wr + i * 32 + lq * 8), c, 0, 0, 0);
        int cc = nt * 16 + lrow;
#pragma unroll
        for (int r = 0; r < 4; ++r) {
            int gr = row0 + lq * 4 + r;
            if (gr < Nn) out[(size_t)gr * 64 + cc] = (_Float16)c[r];
        }
    }
}

// ---------------- z = aggY + h @ W2r^T + lb ----------------
__global__ __launch_bounds__(256) void dense2b_kernel(
    const _Float16* __restrict__ aggY, const _Float16* __restrict__ A2,
    const _Float16* __restrict__ W2, const float* __restrict__ lb,
    _Float16* __restrict__ out) {
    const int t = threadIdx.x;
    const int w = t >> 6, lane = t & 63;
    const int lrow = lane & 15, lq = lane >> 4;
    const int row0 = blockIdx.x * 64 + w * 16;
    const int ld = min(row0 + lrow, Nn - 1);
    f16x8 a[4];
#pragma unroll
    for (int i = 0; i < 4; ++i)
        a[i] = *(const f16x8*)(A2 + (size_t)ld * 128 + i * 32 + lq * 8);
#pragma unroll
    for (int nt = 0; nt < 4; ++nt) {
        const _Float16* wr = W2 + (size_t)(nt * 16 + lrow) * 128;
        f32x4 c = {0.f, 0.f, 0.f, 0.f};
#pragma unroll
        for (int i = 0; i < 4; ++i)
            c = __builtin_amdgcn_mfma_f32_16x16x32_f16(a[i], *(const f16x8*)(wr + i * 32 + lq * 8), c, 0, 0, 0);
        int cc = nt * 16 + lrow;
        float b = lb[cc];
#pragma unroll
        for (int r = 0; r < 4; ++r) {
            int gr = row0 + lq * 4 + r;
            if (gr < Nn) {
                float g = (float)aggY[(size_t)gr * 64 + cc];
                out[(size_t)gr * 64 + cc] = (_Float16)(c[r] + g + b);
            }
        }
    }
}

// ---------------- fused per-edge predictor: persistent, weights in LDS ----
// 512 threads = 8 waves x 16 edges = 128 edges/tile; 1 block/CU (137 KB LDS).
// Weight rows padded to stride K+8 (16B-aligned, bank-uniform ds_read_b128).
#define EPB 128
#define NT  ((Pp + EPB - 1) / EPB)     // 7813
#define EGRID 1024

#define oL_We1 0        // [64][40]   5120
#define oL_We2 5120     // [32][72]   4608
#define oL_W1a 9728     // [128][72]  18432
#define oL_W1b 28160    // [128][72]  18432
#define oL_W1c 46592    // [128][40]  10240
#define oL_Wp2 56832    // [64][136]  17408
#define oL_BN  74240    // 608 f32    2432
#define oL_E1  76672    // [128][72]  18432  (alias U2)
#define oL_E2  95104    // [128][40]  10240
#define oL_ZU  105344   // [128][136] 34816
#define SMEM_BYTES 140160

__global__ __launch_bounds__(512, 1) void edge_kernel(
    const int* __restrict__ pe,
    const float* __restrict__ ef,
    const _Float16* __restrict__ z,      // [N,64]
    const _Float16* __restrict__ w16,
    const float* __restrict__ bnA,
    const float* __restrict__ pb3,
    float* __restrict__ out) {
    __shared__ __align__(16) unsigned char smem[SMEM_BYTES];
    _Float16* LWe1 = (_Float16*)(smem + oL_We1);
    _Float16* LWe2 = (_Float16*)(smem + oL_We2);
    _Float16* LW1a = (_Float16*)(smem + oL_W1a);
    _Float16* LW1b = (_Float16*)(smem + oL_W1b);
    _Float16* LW1c = (_Float16*)(smem + oL_W1c);
    _Float16* LWp2 = (_Float16*)(smem + oL_Wp2);
    float*    LBN  = (float*)(smem + oL_BN);
    _Float16* E1 = (_Float16*)(smem + oL_E1);
    _Float16* E2 = (_Float16*)(smem + oL_E2);
    _Float16* ZU = (_Float16*)(smem + oL_ZU);
    _Float16* U2 = (_Float16*)(smem + oL_E1);   // alias: E1 dead after P3

    const float* bn1s = LBN;        const float* bn1h = LBN + 64;
    const float* bn2s = LBN + 128;  const float* bn2h = LBN + 256;
    const float* bn3s = LBN + 384;  const float* bn3h = LBN + 448;
    const float* eb2g = LBN + 512;  const float* wp3g = LBN + 544;

    const int t = threadIdx.x;
    const int lane = t & 63;
    const int w = t >> 6;          // 0..7
    const int m0 = w * 16;
    const int lrow = lane & 15;
    const int lq = lane >> 4;
    const int er = lane >> 3;      // gather: 8 rows per instruction
    const int seg = lane & 7;      // 16B segment within 128B z-row
    const float pb3v = pb3[0];

    // tile-data loader (registers only; issue before staging barrier is fine)
    auto load_tile = [&](int tl, f16x8* Ga, f16x8* Gb, float4& Ef0, float4& Ef1) -> bool {
        if (tl >= NT) return false;
        int e0 = tl * EPB + m0;
        if (e0 >= Pp) return false;
#pragma unroll
        for (int i = 0; i < 2; ++i) {
            int eg = e0 + i * 8 + er;
            int ai = pe[eg];
            int bi = pe[Pp + eg];
            Ga[i] = *(const f16x8*)(z + (size_t)ai * 64 + seg * 8);
            Gb[i] = *(const f16x8*)(z + (size_t)bi * 64 + seg * 8);
        }
        const float* src = ef + (size_t)(e0 + lrow) * 32 + lq * 8;
        Ef0 = ld4(src); Ef1 = ld4(src + 4);
        return true;
    };

    // ---- prefetch first tile (before staging: overlaps staging latency) ----
    int tile = blockIdx.x;
    f16x8 ga[2], gb[2]; float4 ef0, ef1;
    bool act = load_tile(tile, ga, gb, ef0, ef1);

    // ---- stage weights (padded) + BN consts into LDS ----
    for (int u = t; u < 256; u += 512) { int r = u >> 2, s = u & 3;
        *(f16x8*)(LWe1 + r * 40 + s * 8) = *(const f16x8*)(w16 + oWe1 + r * 32 + s * 8); }
    for (int u = t; u < 256; u += 512) { int r = u >> 3, s = u & 7;
        *(f16x8*)(LWe2 + r * 72 + s * 8) = *(const f16x8*)(w16 + oWe2 + r * 64 + s * 8); }
    for (int u = t; u < 1024; u += 512) { int r = u >> 3, s = u & 7;
        *(f16x8*)(LW1a + r * 72 + s * 8) = *(const f16x8*)(w16 + oW1a + r * 64 + s * 8); }
    for (int u = t; u < 1024; u += 512) { int r = u >> 3, s = u & 7;
        *(f16x8*)(LW1b + r * 72 + s * 8) = *(const f16x8*)(w16 + oW1b + r * 64 + s * 8); }
    for (int u = t; u < 512; u += 512) { int r = u >> 2, s = u & 3;
        *(f16x8*)(LW1c + r * 40 + s * 8) = *(const f16x8*)(w16 + oW1c + r * 32 + s * 8); }
    for (int u = t; u < 1024; u += 512) { int r = u >> 4, s = u & 15;
        *(f16x8*)(LWp2 + r * 136 + s * 8) = *(const f16x8*)(w16 + oWp2 + r * 128 + s * 8); }
    for (int u = t; u < BN_TOTAL; u += 512) LBN[u] = bnA[u];
    __syncthreads();

    // ---- persistent tile loop (no barriers inside; working LDS is wave-private) ----
    for (; tile < NT; tile += EGRID) {
        const int base = tile * EPB;

        // park current gathers into ZU (za cols 0..63, zb 64..127)
        if (act) {
#pragma unroll
            for (int i = 0; i < 2; ++i) {
                int e = m0 + i * 8 + er;
                *(f16x8*)(ZU + e * 136 + seg * 8) = ga[i];
                *(f16x8*)(ZU + e * 136 + 64 + seg * 8) = gb[i];
            }
        }
        // prefetch next tile (overlaps with this tile's compute)
        f16x8 nga[2], ngb[2]; float4 nef0, nef1;
        bool nact = load_tile(tile + EGRID, nga, ngb, nef0, nef1);

        if (act) {
            // ---- P2: e1 = relu(bn(ef @ eW1^T)), [16x32]@[32x64] ----
            {
                f16x8 a = {(_Float16)ef0.x, (_Float16)ef0.y, (_Float16)ef0.z, (_Float16)ef0.w,
                           (_Float16)ef1.x, (_Float16)ef1.y, (_Float16)ef1.z, (_Float16)ef1.w};
#pragma unroll
                for (int nt = 0; nt < 4; ++nt) {
                    f16x8 b = *(const f16x8*)(LWe1 + (nt * 16 + lrow) * 40 + lq * 8);
                    f32x4 c = {0.f, 0.f, 0.f, 0.f};
                    c = __builtin_amdgcn_mfma_f32_16x16x32_f16(a, b, c, 0, 0, 0);
                    int cc = nt * 16 + lrow;
                    float s = bn1s[cc], h = bn1h[cc];
#pragma unroll
                    for (int r = 0; r < 4; ++r) {
                        int rr = m0 + lq * 4 + r;
                        E1[rr * 72 + cc] = (_Float16)fmaxf(c[r] * s + h, 0.f);
                    }
                }
            }
            // ---- P3: e2 = e1 @ eW2^T + eb2, [16x64]@[64x32] ----
            {
                f16x8 a0 = *(const f16x8*)(E1 + (m0 + lrow) * 72 + lq * 8);
                f16x8 a1 = *(const f16x8*)(E1 + (m0 + lrow) * 72 + 32 + lq * 8);
#pragma unroll
                for (int nt = 0; nt < 2; ++nt) {
                    f16x8 b0 = *(const f16x8*)(LWe2 + (nt * 16 + lrow) * 72 + lq * 8);
                    f16x8 b1 = *(const f16x8*)(LWe2 + (nt * 16 + lrow) * 72 + 32 + lq * 8);
                    f32x4 c = {0.f, 0.f, 0.f, 0.f};
                    c = __builtin_amdgcn_mfma_f32_16x16x32_f16(a0, b0, c, 0, 0, 0);
                    c = __builtin_amdgcn_mfma_f32_16x16x32_f16(a1, b1, c, 0, 0, 0);
                    int cc = nt * 16 + lrow;
                    float bias = eb2g[cc];
#pragma unroll
                    for (int r = 0; r < 4; ++r) {
                        int rr = m0 + lq * 4 + r;
                        E2[rr * 40 + cc] = (_Float16)(c[r] + bias);
                    }
                }
            }
            // ---- P4: u1 = relu(bn1(za@W1a^T + zb@W1b^T + e2@W1c^T)), NOUT=128 ----
            {
                f16x8 za0 = *(const f16x8*)(ZU + (m0 + lrow) * 136 + lq * 8);
                f16x8 za1 = *(const f16x8*)(ZU + (m0 + lrow) * 136 + 32 + lq * 8);
                f16x8 zb0 = *(const f16x8*)(ZU + (m0 + lrow) * 136 + 64 + lq * 8);
                f16x8 zb1 = *(const f16x8*)(ZU + (m0 + lrow) * 136 + 96 + lq * 8);
                f16x8 ae  = *(const f16x8*)(E2 + (m0 + lrow) * 40 + lq * 8);
#pragma unroll
                for (int nt = 0; nt < 8; ++nt) {
                    const _Float16* wa = LW1a + (nt * 16 + lrow) * 72;
                    const _Float16* wb = LW1b + (nt * 16 + lrow) * 72;
                    const _Float16* wc = LW1c + (nt * 16 + lrow) * 40;
                    f32x4 c = {0.f, 0.f, 0.f, 0.f};
                    c = __builtin_amdgcn_mfma_f32_16x16x32_f16(za0, *(const f16x8*)(wa + lq * 8),      c, 0, 0, 0);
                    c = __builtin_amdgcn_mfma_f32_16x16x32_f16(za1, *(const f16x8*)(wa + 32 + lq * 8), c, 0, 0, 0);
                    c = __builtin_amdgcn_mfma_f32_16x16x32_f16(zb0, *(const f16x8*)(wb + lq * 8),      c, 0, 0, 0);
                    c = __builtin_amdgcn_mfma_f32_16x16x32_f16(zb1, *(const f16x8*)(wb + 32 + lq * 8), c, 0, 0, 0);
                    c = __builtin_amdgcn_mfma_f32_16x16x32_f16(ae,  *(const f16x8*)(wc + lq * 8),      c, 0, 0, 0);
                    int cc = nt * 16 + lrow;
                    float s = bn2s[cc], h = bn2h[cc];
#pragma unroll
                    for (int r = 0; r < 4; ++r) {
                        int rr = m0 + lq * 4 + r;
                        ZU[rr * 136 + cc] = (_Float16)fmaxf(c[r] * s + h, 0.f);
                    }
                }
            }
            // ---- P6: u2 = relu(bn2(u1 @ pW2^T)), [16x128]@[128x64] ----
            {
                f16x8 a0 = *(const f16x8*)(ZU + (m0 + lrow) * 136 + 0  + lq * 8);
                f16x8 a1 = *(const f16x8*)(ZU + (m0 + lrow) * 136 + 32 + lq * 8);
                f16x8 a2 = *(const f16x8*)(ZU + (m0 + lrow) * 136 + 64 + lq * 8);
                f16x8 a3 = *(const f16x8*)(ZU + (m0 + lrow) * 136 + 96 + lq * 8);
#pragma unroll
                for (int nt = 0; nt < 4; ++nt) {
                    const _Float16* wr = LWp2 + (nt * 16 + lrow) * 136 + lq * 8;
                    f32x4 c = {0.f, 0.f, 0.f, 0.f};
                    c = __builtin_amdgcn_mfma_f32_16x16x32_f16(a0, *(const f16x8*)(wr + 0),  c, 0, 0, 0);
                    c = __builtin_amdgcn_mfma_f32_16x16x32_f16(a1, *(const f16x8*)(wr + 32), c, 0, 0, 0);
                    c = __builtin_amdgcn_mfma_f32_16x16x32_f16(a2, *(const f16x8*)(wr + 64), c, 0, 0, 0);
                    c = __builtin_amdgcn_mfma_f32_16x16x32_f16(a3, *(const f16x8*)(wr + 96), c, 0, 0, 0);
                    int cc = nt * 16 + lrow;
                    float s = bn3s[cc], h = bn3h[cc];
#pragma unroll
                    for (int r = 0; r < 4; ++r) {
                        int rr = m0 + lq * 4 + r;
                        U2[rr * 72 + cc] = (_Float16)fmaxf(c[r] * s + h, 0.f);
                    }
                }
            }
            // ---- P7: out = u2 @ pW3 + pb3 (4 lanes per edge) ----
            {
                int e = m0 + (lane >> 2);
                int c0 = (lane & 3) * 16;
                f16x8 u0 = *(const f16x8*)(U2 + e * 72 + c0);
                f16x8 u1 = *(const f16x8*)(U2 + e * 72 + c0 + 8);
                float acc = 0.f;
#pragma unroll
                for (int j = 0; j < 8; ++j) acc += (float)u0[j] * wp3g[c0 + j];
#pragma unroll
                for (int j = 0; j < 8; ++j) acc += (float)u1[j] * wp3g[c0 + 8 + j];
                acc += __shfl_xor(acc, 1);
                acc += __shfl_xor(acc, 2);
                if ((lane & 3) == 0) out[base + e] = acc + pb3v;
            }
        }
        // rotate prefetch -> current
        ga[0] = nga[0]; ga[1] = nga[1];
        gb[0] = ngb[0]; gb[1] = ngb[1];
        ef0 = nef0; ef1 = nef1;
        act = nact;
    }
}

// ---------------- launch ----------------
extern "C" void kernel_launch(void* const* d_in, const int* in_sizes, int n_in,
                              void* d_out, int out_size, void* d_ws, size_t ws_size,
                              hipStream_t stream) {
    const float* x    = (const float*)d_in[0];
    const int*   eidx = (const int*)d_in[1];
    const int*   pe   = (const int*)d_in[2];
    const float* ef   = (const float*)d_in[3];
    const float* s1Wl = (const float*)d_in[4];
    const float* s1bl = (const float*)d_in[5];
    const float* s1Wr = (const float*)d_in[6];
    const float* bn1g = (const float*)d_in[7];
    const float* bn1b = (const float*)d_in[8];
    const float* bn1m = (const float*)d_in[9];
    const float* bn1v = (const float*)d_in[10];
    const float* s2Wl = (const float*)d_in[11];
    const float* s2bl = (const float*)d_in[12];
    const float* s2Wr = (const float*)d_in[13];
    const float* eW1  = (const float*)d_in[14];
    const float* eb1  = (const float*)d_in[15];
    const float* ebng = (const float*)d_in[16];
    const float* ebnb = (const float*)d_in[17];
    const float* ebnm = (const float*)d_in[18];
    const float* ebnv = (const float*)d_in[19];
    const float* eW2  = (const float*)d_in[20];
    const float* eb2  = (const float*)d_in[21];
    const float* pW1  = (const float*)d_in[22];
    const float* pb1  = (const float*)d_in[23];
    const float* p1g  = (const float*)d_in[24];
    const float* p1b  = (const float*)d_in[25];
    const float* p1m  = (const float*)d_in[26];
    const float* p1v  = (const float*)d_in[27];
    const float* pW2  = (const float*)d_in[28];
    const float* pb2  = (const float*)d_in[29];
    const float* p2g  = (const float*)d_in[30];
    const float* p2b  = (const float*)d_in[31];
    const float* p2m  = (const float*)d_in[32];
    const float* p2v  = (const float*)d_in[33];
    const float* pW3  = (const float*)d_in[34];
    const float* pb3  = (const float*)d_in[35];
    float* out = (float*)d_out;

    char* wk = (char*)d_ws;
    auto carve = [&](size_t bytes) {
        char* p = wk;
        wk += (bytes + 255) & ~(size_t)255;
        return p;
    };
    unsigned*  deg    = (unsigned*)carve((size_t)Nn * 4);
    int*       rowptr = (int*)carve((size_t)(Nn + 1) * 4);
    int*       cursor = (int*)carve((size_t)Nn * 4);
    int*       elist  = (int*)carve((size_t)Ee * 4);
    unsigned*  escan  = (unsigned*)carve((size_t)Nn * 4);
    unsigned*  bsum   = (unsigned*)carve(128 * 4);
    unsigned*  boff   = (unsigned*)carve(128 * 4);
    _Float16*  w16    = (_Float16*)carve((size_t)W16_TOTAL * 2);
    float*     bnA    = (float*)carve((size_t)BN_TOTAL * 4);
    _Float16*  bufX   = (_Float16*)carve((size_t)Nn * 128 * 2);  // x16; later y|z
    _Float16*  bufA   = (_Float16*)carve((size_t)Nn * 128 * 2);  // agg1 out; later aggY
    _Float16*  bufH   = (_Float16*)carve((size_t)Nn * 128 * 2);  // h
    _Float16*  bufY   = bufX;
    _Float16*  bufZ   = bufX + (size_t)Nn * 64;
    _Float16*  bufAy  = bufA;

    const int* e_src = eidx;
    const int* e_dst = eidx + Ee;
    const int SBLK = (Nn + 1023) / 1024;   // 98

    hipMemsetAsync(deg, 0, (size_t)Nn * 4, stream);
    prep_kernel<<<800, 256, 0, stream>>>(x, s1Wl, s1Wr, s2Wl, s2Wr, pW1, eW1, eW2, pW2,
                                         eb1, ebng, ebnb, ebnm, ebnv, eb2,
                                         pb1, p1g, p1b, p1m, p1v,
                                         pb2, p2g, p2b, p2m, p2v, pW3,
                                         w16, bnA, bufX);
    hist_kernel<<<(Ee + 255) / 256, 256, 0, stream>>>(e_dst, deg);
    scanA_kernel<<<SBLK, 1024, 0, stream>>>(deg, escan, bsum);
    scanB_kernel<<<1, 128, 0, stream>>>(bsum, boff, SBLK);
    scanC_kernel<<<SBLK, 1024, 0, stream>>>(escan, boff, rowptr, cursor);
    scatter_kernel<<<(Ee + 255) / 256, 256, 0, stream>>>(e_src, e_dst, cursor, elist);

    // SAGE layer 1
    aggregate16_kernel<128><<<Nn / 4, 256, 0, stream>>>(bufX, rowptr, elist, bufA);
    dense1_kernel<<<(Nn + 63) / 64, 256, 0, stream>>>(
        bufA, bufX, w16 + oW1l, w16 + oW1r, s1bl, bn1g, bn1b, bn1m, bn1v, bufH);

    // SAGE layer 2 (linear commutes with mean)
    gemmY_kernel<<<(Nn + 63) / 64, 256, 0, stream>>>(bufH, w16 + oW2l, bufY);
    aggregate16_kernel<64><<<Nn / 4, 256, 0, stream>>>(bufY, rowptr, elist, bufAy);
    dense2b_kernel<<<(Nn + 63) / 64, 256, 0, stream>>>(
        bufAy, bufH, w16 + oW2r, s2bl, bufZ);

    // fused per-edge predictor (persistent, weights in LDS)
    edge_kernel<<<EGRID, 512, 0, stream>>>(pe, ef, bufZ, w16, bnA, pb3, out);
}